// Round 14
// baseline (303.858 us; speedup 1.0000x reference)
//
#include <hip/hip_runtime.h>
#include <math.h>

// Problem constants
#define HH 16
#define BB 4
#define LL 4096
#define DD 1024
#define DK 64
#define MMF 256
#define EPSF 1e-6f
// orf scale: 64^-0.25 * log2(e)  (phi computed as exp2)
#define KSCALE (0.35355339059327373f * 1.4426950408889634f)
// norm scale: 1/(2*sqrt(64)) * log2(e)
#define NORMSCALE (0.0625f * 1.4426950408889634f)
#define NSPLIT 8
#define LCH (LL / NSPLIT)             // 512 rows of L per kv block

typedef __attribute__((ext_vector_type(8))) short bf16x8;
typedef __attribute__((ext_vector_type(4))) float f32x4;
typedef __attribute__((ext_vector_type(8))) unsigned short u16x8;

__device__ __forceinline__ unsigned short f2bf(float f) {
  union { float f; unsigned u; } v; v.f = f;
  unsigned r = v.u + 0x7FFF + ((v.u >> 16) & 1);   // RNE
  return (unsigned short)(r >> 16);
}
__device__ __forceinline__ float bf2f(unsigned short h) {
  union { unsigned u; float f; } v; v.u = ((unsigned)h) << 16;
  return v.f;
}
__device__ __forceinline__ f32x4 mfma16(bf16x8 a, bf16x8 b, f32x4 c) {
  return __builtin_amdgcn_mfma_f32_16x16x32_bf16(a, b, c, 0, 0, 0);
}
// single v_exp_f32 (exp2f routes through OCML's precise multi-inst path)
__device__ __forceinline__ float fexp2(float x) {
  return __builtin_amdgcn_exp2f(x);
}
// async global->LDS, 16B per lane; dst is wave-uniform base (lane x16 implicit)
__device__ __forceinline__ void gload16(const unsigned short* g, unsigned short* l) {
  __builtin_amdgcn_global_load_lds(
      (const __attribute__((address_space(1))) void*)g,
      (__attribute__((address_space(3))) void*)l, 16, 0, 0);
}
// T2 swizzle for 64-element bf16 rows (element-index xor)
#define SWZ(row, col) ((col) ^ (((row) & 7) << 3))

// ---------------------------------------------------------------------------
// fp32 -> bf16 conversion (n multiple of 4)
// ---------------------------------------------------------------------------
__global__ __launch_bounds__(256) void cvt_bf16(
    const float* __restrict__ src, unsigned short* __restrict__ dst, int n) {
  int i = (blockIdx.x * 256 + threadIdx.x) * 4;
  if (i < n) {
    float4 v = *(const float4*)&src[i];
    ushort4 o;
    o.x = f2bf(v.x); o.y = f2bf(v.y); o.z = f2bf(v.z); o.w = f2bf(v.w);
    *(ushort4*)&dst[i] = o;
  }
}

// fused 4-way weight conversion, grid (1024, 4)
__global__ __launch_bounds__(256) void cvt_bf16_w(
    const float* __restrict__ W0, const float* __restrict__ W1,
    const float* __restrict__ W2, const float* __restrict__ W3,
    unsigned short* __restrict__ D0, unsigned short* __restrict__ D1,
    unsigned short* __restrict__ D2, unsigned short* __restrict__ D3) {
  const float* s;
  unsigned short* d;
  switch (blockIdx.y) {
    case 0: s = W0; d = D0; break;
    case 1: s = W1; d = D1; break;
    case 2: s = W2; d = D2; break;
    default: s = W3; d = D3; break;
  }
  int i = (blockIdx.x * 256 + threadIdx.x) * 4;
  float4 v = *(const float4*)&s[i];
  ushort4 o;
  o.x = f2bf(v.x); o.y = f2bf(v.y); o.z = f2bf(v.z); o.w = f2bf(v.w);
  *(ushort4*)&d[i] = o;
}

// orf: scale by KSCALE (dk^-.25 * log2e), bf16
__global__ __launch_bounds__(256) void cvt_orf(
    const float* __restrict__ src, unsigned short* __restrict__ hi, int n) {
  int i = blockIdx.x * 256 + threadIdx.x;
  if (i < n) hi[i] = f2bf(src[i] * KSCALE);
}

// ---------------------------------------------------------------------------
// bf16 MFMA GEMM, 256x128 tile, BK=64, 8 waves (4Mx2N), wave tile 64x64.
// TRI-BUFFERED LDS, 3 x 48KB = 144KB (A 256x64 = 32KB, B 128x64 = 16KB):
// tile kt+2's 6 gload16 issued during tile kt; boundary wait vmcnt(6)
// (kt+1's loads only — kt+2's stay in flight). ONE barrier per K-tile.
// Grid 64x8 = 512 blocks, bijective XCD swizzle.
// Epilogue: per-wave LDS-transpose (64x64 wave tile, r11-proven code).
// MODE 0: fp32 C row-major.
// MODE 1: bf16 transposed Ct[(b*16+h)*64+d][4096]                  (V path)
// MODE 2: hi/lo bf16 [bh][l][64] + norms[bh][l] (pre *log2e/16)    (Q,K paths)
// ---------------------------------------------------------------------------
template <int MODE>
__global__ __launch_bounds__(512, 2) void gemm_mfma(
    const unsigned short* __restrict__ A, const unsigned short* __restrict__ W,
    const float* __restrict__ bias, float* __restrict__ Cf,
    unsigned short* __restrict__ C1, unsigned short* __restrict__ C2,
    float* __restrict__ Cn, int M, int N, int K) {
  // 3 buffers x 24576 ushorts (A 16384 | B 8192); epilogue reuses front 70KB
  __shared__ __align__(16) char smem[147456];
  unsigned short* S = (unsigned short*)smem;
  const int tid = threadIdx.x, lane = tid & 63;
  const int w = tid >> 6;                 // 0..7
  const int wm = w >> 1, wn = w & 1;      // 4 M x 2 N waves
  const int g = lane >> 4, li = lane & 15;
  // bijective XCD swizzle: 512 blocks; each XCD: 8 m-panels x 8 n-panels
  const int flat = blockIdx.y * gridDim.x + blockIdx.x;   // 0..511
  const int xcd = flat & 7, loc = flat >> 3;              // loc 0..63
  const int m0 = (xcd * 8 + (loc & 7)) * 256;
  const int n0 = (loc >> 3) * 128;

  f32x4 acc[4][4] = {};
  const int srow8 = lane >> 3;                    // row within 8-row group
  const int scol  = ((lane & 7) ^ srow8) << 3;    // pre-swizzled element col
  const unsigned short* Ast = A + (size_t)(m0 + w * 32 + srow8) * K + scol;
  const unsigned short* Wst = W + (size_t)(n0 + w * 16 + srow8) * K + scol;
  const int nt = K >> 6;                  // 16
  const int sx = (li & 7) << 3;

  // stage one K-tile into buffer `buf`: A rows w*32..+31 (4), B rows w*16..+15 (2)
#define STAGE(buf, kt_)                                                        \
  {                                                                            \
    const size_t ko_ = (size_t)(kt_) << 6;                                     \
    _Pragma("unroll")                                                          \
    for (int gi = 0; gi < 4; ++gi)                                             \
      gload16(Ast + (size_t)gi * 8 * K + ko_,                                  \
              S + (buf) + (w * 32 + gi * 8) * 64);                             \
    _Pragma("unroll")                                                          \
    for (int gi = 0; gi < 2; ++gi)                                             \
      gload16(Wst + (size_t)gi * 8 * K + ko_,                                  \
              S + (buf) + 16384 + (w * 16 + gi * 8) * 64);                     \
  }

  // prologue: stage tiles 0 and 1
  STAGE(0, 0)
  STAGE(24576, 1)
  asm volatile("s_waitcnt vmcnt(6)" ::: "memory");   // tile 0 landed
  __builtin_amdgcn_s_barrier();

  int b0 = 0, b1 = 24576, b2 = 49152;    // rotating buffer offsets (ushorts)
  for (int kt = 0; kt < nt; ++kt) {
    // issue tile kt+2 into b2 (its old contents fully read at end of kt-1)
    if (kt + 2 < nt) STAGE(b2, kt + 2)
    // compute both K-halves from b0
#pragma unroll
    for (int kk = 0; kk < 2; ++kk) {
      const int c = (kk * 32 + g * 8) ^ sx;
      bf16x8 af[4], bfr[4];
#pragma unroll
      for (int i = 0; i < 4; ++i)
        af[i] = *(const bf16x8*)&S[b0 + (wm * 64 + i * 16 + li) * 64 + c];
#pragma unroll
      for (int j = 0; j < 4; ++j)
        bfr[j] = *(const bf16x8*)&S[b0 + 16384 + (wn * 64 + j * 16 + li) * 64 + c];
      __builtin_amdgcn_s_setprio(1);
#pragma unroll
      for (int i = 0; i < 4; ++i)
#pragma unroll
        for (int j = 0; j < 4; ++j)
          acc[i][j] = mfma16(af[i], bfr[j], acc[i][j]);
      __builtin_amdgcn_s_setprio(0);
    }
    // my reads of b0 complete before anyone re-stages it next iteration
    asm volatile("s_waitcnt lgkmcnt(0)" ::: "memory");
    // counted wait: tile kt+1's 6 loads (issued a full tile ago) must be in;
    // tile kt+2's 6 stay in flight across the barrier (never drain to 0)
    if (kt + 2 < nt) {
      asm volatile("s_waitcnt vmcnt(6)" ::: "memory");
    } else if (kt + 1 < nt) {
      asm volatile("s_waitcnt vmcnt(0)" ::: "memory");
    }
    __builtin_amdgcn_s_barrier();
    const int tmp = b0; b0 = b1; b1 = b2; b2 = tmp;
  }

  // -------- epilogue: LDS transpose, coalesced stores (r11 64x64 form) ------
  float* ep = (float*)smem + w * (32 * 68);   // 8 waves x 8704B = 69632B
  const int head = (n0 + wn * 64) >> 6;
  const int rbase = m0 + wm * 64;       // global row base of this wave's tile
  const int b = rbase >> 12;            // batch (tile never crosses b boundary)

  if (MODE == 2) {
#pragma unroll
    for (int jh = 0; jh < 2; ++jh) {
#pragma unroll
      for (int i2 = 0; i2 < 2; ++i2) {
        const int i = jh * 2 + i2;
#pragma unroll
        for (int j = 0; j < 4; ++j) {
          const float bz = bias[n0 + wn * 64 + j * 16 + li];
#pragma unroll
          for (int r = 0; r < 4; ++r)
            ep[(i2 * 16 + 4 * g + r) * 68 + j * 16 + li] = acc[i][j][r] + bz;
        }
      }
      const int rrow = lane >> 3, cc = lane & 7;
#pragma unroll
      for (int p = 0; p < 4; ++p) {
        const int row = p * 8 + rrow;
        float v[8];
        *(f32x4*)&v[0] = *(const f32x4*)&ep[row * 68 + cc * 8];
        *(f32x4*)&v[4] = *(const f32x4*)&ep[row * 68 + cc * 8 + 4];
        float np = 0.f;
        u16x8 hv, lv;
#pragma unroll
        for (int e = 0; e < 8; ++e) {
          float vv = v[e];
          np += vv * vv;
          unsigned short h = f2bf(vv);
          hv[e] = h;
          lv[e] = f2bf(vv - bf2f(h));
        }
        const int lg = (rbase + jh * 32 + row) & 4095;
        const size_t rowb = (size_t)(b * 16 + head) * 4096 + lg;
        *(u16x8*)&C1[rowb * 64 + cc * 8] = hv;
        *(u16x8*)&C2[rowb * 64 + cc * 8] = lv;
        np += __shfl_xor(np, 1);
        np += __shfl_xor(np, 2);
        np += __shfl_xor(np, 4);
        if (cc == 0) Cn[rowb] = np * NORMSCALE;
      }
    }
  } else if (MODE == 1) {
#pragma unroll
    for (int jh = 0; jh < 2; ++jh) {
#pragma unroll
      for (int i = 0; i < 4; ++i)
#pragma unroll
        for (int j2 = 0; j2 < 2; ++j2) {
          const int j = jh * 2 + j2;
          const float bz = bias[n0 + wn * 64 + j * 16 + li];
          f32x4 t;
          t[0] = acc[i][j][0] + bz; t[1] = acc[i][j][1] + bz;
          t[2] = acc[i][j][2] + bz; t[3] = acc[i][j][3] + bz;
          *(f32x4*)&ep[(j2 * 16 + li) * 68 + i * 16 + 4 * g] = t;
        }
      const int rd = lane >> 3, cc = lane & 7;
#pragma unroll
      for (int p = 0; p < 4; ++p) {
        const int dl = p * 8 + rd;
        float v[8];
        *(f32x4*)&v[0] = *(const f32x4*)&ep[dl * 68 + cc * 8];
        *(f32x4*)&v[4] = *(const f32x4*)&ep[dl * 68 + cc * 8 + 4];
        u16x8 hv;
#pragma unroll
        for (int e = 0; e < 8; ++e) hv[e] = f2bf(v[e]);
        const int dh = jh * 32 + dl;
        const int lg = rbase & 4095;
        *(u16x8*)&C1[((size_t)(b * 16 + head) * 64 + dh) * 4096 + lg + cc * 8] = hv;
      }
    }
  } else {  // MODE 0: fp32 row-major
#pragma unroll
    for (int jh = 0; jh < 2; ++jh) {
#pragma unroll
      for (int i2 = 0; i2 < 2; ++i2) {
        const int i = jh * 2 + i2;
#pragma unroll
        for (int j = 0; j < 4; ++j) {
          const float bz = bias[n0 + wn * 64 + j * 16 + li];
#pragma unroll
          for (int r = 0; r < 4; ++r)
            ep[(i2 * 16 + 4 * g + r) * 68 + j * 16 + li] = acc[i][j][r] + bz;
        }
      }
      const int rrow = lane >> 4, cc = lane & 15;
#pragma unroll
      for (int p = 0; p < 8; ++p) {
        const int row = p * 4 + rrow;
        f32x4 v = *(const f32x4*)&ep[row * 68 + cc * 4];
        *(f32x4*)&Cf[(size_t)(rbase + jh * 32 + row) * 1024 + n0 + wn * 64 + cc * 4] = v;
      }
    }
  }
#undef STAGE
}

// ---------------------------------------------------------------------------
// kv + ksum. grid (64 bh, NSPLIT), 256 thr / 4 waves. 2-TERM proj split:
// oh*(khi + klo). phi via single v_exp_f32. (r11 structure, unchanged)
// ---------------------------------------------------------------------------
__global__ __launch_bounds__(256, 2) void kv_mfma(
    const unsigned short* __restrict__ khi, const unsigned short* __restrict__ klo,
    const float* __restrict__ knorms, const unsigned short* __restrict__ vt,
    const unsigned short* __restrict__ orfhi,
    float* __restrict__ pkv, float* __restrict__ pksum) {
  __shared__ __align__(16) unsigned short KsHi[64 * 64], KsLo[64 * 64];
  __shared__ __align__(16) unsigned short VT[64 * 64], KphiT[64 * 64];
  __shared__ float ns[64];
  const int tid = threadIdx.x, lane = tid & 63, w = tid >> 6;
  const int g = lane >> 4, li = lane & 15;
  const int bh = blockIdx.x, sp = blockIdx.y;
  const int srow8 = lane >> 3;
  const int scol  = ((lane & 7) ^ srow8) << 3;
  const int sx = (li & 7) << 3;

  bf16x8 oh[4][2];
#pragma unroll
  for (int p = 0; p < 4; ++p)
#pragma unroll
    for (int kk = 0; kk < 2; ++kk)
      oh[p][kk] = *(const bf16x8*)
          &orfhi[(size_t)(p * 64 + w * 16 + li) * 64 + kk * 32 + g * 8];

  f32x4 kvacc[4][4] = {};
  float ksacc[4][4] = {};

  for (int c = 0; c < LCH / 64; ++c) {
    const int l0 = sp * LCH + c * 64;
    __syncthreads();
    {
      const size_t kb = ((size_t)bh * 4096 + l0 + w * 16 + srow8) * 64 + scol;
      gload16(khi + kb, &KsHi[(w * 16) * 64]);
      gload16(khi + kb + 8 * 64, &KsHi[(w * 16 + 8) * 64]);
      gload16(klo + kb, &KsLo[(w * 16) * 64]);
      gload16(klo + kb + 8 * 64, &KsLo[(w * 16 + 8) * 64]);
      const size_t vb = ((size_t)bh * 64 + w * 16 + srow8) * 4096 + l0 + scol;
      gload16(vt + vb, &VT[(w * 16) * 64]);
      gload16(vt + vb + (size_t)8 * 4096, &VT[(w * 16 + 8) * 64]);
      if (tid < 64) ns[tid] = knorms[(size_t)bh * 4096 + l0 + tid];
    }
    __syncthreads();

#pragma unroll
    for (int p = 0; p < 4; ++p) {
      f32x4 pr[4] = {};
      __builtin_amdgcn_s_setprio(1);
#pragma unroll
      for (int kk = 0; kk < 2; ++kk) {
        const int cx = (kk * 32 + g * 8) ^ sx;
#pragma unroll
        for (int lf = 0; lf < 4; ++lf) {
          const bf16x8 bh2 = *(const bf16x8*)&KsHi[(lf * 16 + li) * 64 + cx];
          const bf16x8 bl2 = *(const bf16x8*)&KsLo[(lf * 16 + li) * 64 + cx];
          pr[lf] = mfma16(oh[p][kk], bh2, pr[lf]);
          pr[lf] = mfma16(oh[p][kk], bl2, pr[lf]);
        }
      }
      __builtin_amdgcn_s_setprio(0);
#pragma unroll
      for (int lf = 0; lf < 4; ++lf) {
        const float nrm = ns[lf * 16 + li];
#pragma unroll
        for (int r = 0; r < 4; ++r) {
          float phi = fexp2(pr[lf][r] - nrm) + EPSF;
          ksacc[p][r] += phi;
          const int row = w * 16 + 4 * g + r;
          KphiT[row * 64 + SWZ(row, lf * 16 + li)] = f2bf(phi);
        }
      }
      __builtin_amdgcn_s_setprio(1);
#pragma unroll
      for (int kk = 0; kk < 2; ++kk) {
        const int cx = (kk * 32 + g * 8) ^ sx;
        const bf16x8 a = *(const bf16x8*)&KphiT[(w * 16 + li) * 64 + cx];
#pragma unroll
        for (int df = 0; df < 4; ++df) {
          const bf16x8 bv = *(const bf16x8*)&VT[(df * 16 + li) * 64 + cx];
          kvacc[p][df] = mfma16(a, bv, kvacc[p][df]);
        }
      }
      __builtin_amdgcn_s_setprio(0);
    }
  }
  float* kvo = pkv + ((size_t)sp * 64 + bh) * (MMF * DK);
#pragma unroll
  for (int p = 0; p < 4; ++p)
#pragma unroll
    for (int df = 0; df < 4; ++df)
#pragma unroll
      for (int r = 0; r < 4; ++r)
        kvo[(p * 64 + w * 16 + 4 * g + r) * DK + df * 16 + li] = kvacc[p][df][r];

  float* kso = pksum + ((size_t)sp * 64 + bh) * MMF;
#pragma unroll
  for (int p = 0; p < 4; ++p)
#pragma unroll
    for (int r = 0; r < 4; ++r) {
      float s = ksacc[p][r];
      s += __shfl_xor(s, 1); s += __shfl_xor(s, 2);
      s += __shfl_xor(s, 4); s += __shfl_xor(s, 8);
      if (li == 0) kso[p * 64 + w * 16 + 4 * g + r] = s;
    }
}

// ---------------------------------------------------------------------------
// reduce partials; emit kv TRANSPOSED bf16 kvT[bh][d][m] + ksum fp32
// ---------------------------------------------------------------------------
__global__ __launch_bounds__(256) void reduce_parts(
    const float* __restrict__ pkv, unsigned short* __restrict__ kvT,
    const float* __restrict__ pks, float* __restrict__ ksg) {
  const int id = blockIdx.x * 256 + threadIdx.x;   // grid 1024 -> 262144
  {
    const int bh = id >> 12, rest = id & 4095;
    const int m0 = (rest >> 6) << 2, d = rest & 63;
    float s0 = 0.f, s1 = 0.f, s2 = 0.f, s3 = 0.f;
#pragma unroll
    for (int sp = 0; sp < NSPLIT; ++sp) {
      const float* p = pkv + (size_t)(sp * 64 + bh) * (MMF * DK) + d;
      s0 += p[(m0 + 0) * DK]; s1 += p[(m0 + 1) * DK];
      s2 += p[(m0 + 2) * DK]; s3 += p[(m0 + 3) * DK];
    }
    ushort4 o;
    o.x = f2bf(s0); o.y = f2bf(s1); o.z = f2bf(s2); o.w = f2bf(s3);
    *(ushort4*)&kvT[((size_t)bh * DK + d) * MMF + m0] = o;
  }
  if (id < 4096) {
    float4 s = {0.f, 0.f, 0.f, 0.f};
#pragma unroll
    for (int sp = 0; sp < NSPLIT; ++sp) {
      float4 v = *(const float4*)&pks[(size_t)sp * 64 * MMF + id * 4];
      s.x += v.x; s.y += v.y; s.z += v.z; s.w += v.w;
    }
    *(float4*)&ksg[id * 4] = s;
  }
}

// ---------------------------------------------------------------------------
// q_phi + num/den -> attn (bf16). grid (64 bh, 32 l-blocks), 512 threads.
// (r11 structure, unchanged)
// ---------------------------------------------------------------------------
__global__ __launch_bounds__(512, 4) void qattn_mfma(
    const unsigned short* __restrict__ qhi, const unsigned short* __restrict__ qlo,
    const float* __restrict__ qnorms,
    const unsigned short* __restrict__ orfhi,
    const unsigned short* __restrict__ kvT, const float* __restrict__ ksg,
    unsigned short* __restrict__ attn) {
  __shared__ __align__(16) unsigned short OHi[256 * 64];    // 32 KB
  __shared__ __align__(16) unsigned short KvTs[64 * 256];   // 32 KB
  __shared__ __align__(16) unsigned short Qphi[8][16 * 64]; // 16 KB
  const int tid = threadIdx.x, lane = tid & 63, w = tid >> 6;
  const int g = lane >> 4, li = lane & 15;
  const int bh = blockIdx.x, lb = blockIdx.y;
  const int b = bh >> 4, h = bh & 15;
  const int srow8 = lane >> 3;
  const int scol  = ((lane & 7) ^ srow8) << 3;
  const int sx = (li & 7) << 3;

#pragma unroll
  for (int q = 0; q < 4; ++q) {
    const size_t o = (size_t)(w * 32 + q * 8 + srow8) * 64 + scol;
    gload16(orfhi + o, &OHi[(w * 32 + q * 8) * 64]);
  }
  {
    const int srow2 = lane >> 5;
#pragma unroll
    for (int q = 0; q < 4; ++q) {
      const int d0 = w * 8 + q * 2, dr = d0 + srow2;
      gload16(kvT + ((size_t)bh * DK + dr) * MMF + (((lane & 31) ^ (dr & 7)) << 3),
              &KvTs[d0 * 256]);
    }
  }

  float ksr[4][4];
#pragma unroll
  for (int p = 0; p < 4; ++p)
#pragma unroll
    for (int mf = 0; mf < 4; ++mf)
      ksr[p][mf] = ksg[(size_t)bh * MMF + p * 64 + mf * 16 + li];
  const float4 nr =
      *(const float4*)&qnorms[(size_t)bh * 4096 + lb * 128 + w * 16 + 4 * g];
  bf16x8 qh[2], ql[2];
  {
    const size_t qr = ((size_t)bh * 4096 + lb * 128 + w * 16 + li) * 64 + g * 8;
    qh[0] = *(const bf16x8*)&qhi[qr];
    qh[1] = *(const bf16x8*)&qhi[qr + 32];
    ql[0] = *(const bf16x8*)&qlo[qr];
    ql[1] = *(const bf16x8*)&qlo[qr + 32];
  }
  __syncthreads();

  f32x4 numacc[4] = {};
  float denacc[4] = {};

#pragma unroll
  for (int p = 0; p < 4; ++p) {
    f32x4 pr[4] = {};
    __builtin_amdgcn_s_setprio(1);
#pragma unroll
    for (int kk = 0; kk < 2; ++kk) {
      const int cx = (kk * 32 + g * 8) ^ sx;
#pragma unroll
      for (int mf = 0; mf < 4; ++mf) {
        const int row = p * 64 + mf * 16 + li;
        const bf16x8 bh2 = *(const bf16x8*)&OHi[row * 64 + cx];
        pr[mf] = mfma16(qh[kk], bh2, pr[mf]);
        pr[mf] = mfma16(ql[kk], bh2, pr[mf]);
      }
    }
    __builtin_amdgcn_s_setprio(0);
#pragma unroll
    for (int mf = 0; mf < 4; ++mf) {
      const float ks = ksr[p][mf];
#pragma unroll
      for (int r = 0; r < 4; ++r) {
        float phi = fexp2(pr[mf][r] - nr[r]) + EPSF;
        denacc[r] += phi * ks;
        const int row = 4 * g + r;
        Qphi[w][row * 64 + SWZ(row, mf * 16 + li)] = f2bf(phi);
      }
    }
    __builtin_amdgcn_s_setprio(1);
#pragma unroll
    for (int kk = 0; kk < 2; ++kk) {
      const int cx = (kk * 32 + g * 8) ^ sx;
      const bf16x8 a = *(const bf16x8*)&Qphi[w][li * 64 + cx];
#pragma unroll
      for (int df = 0; df < 4; ++df) {
        const bf16x8 bv = *(const bf16x8*)
            &KvTs[(df * 16 + li) * 256 + (((p * 8 + kk * 4 + g) ^ (li & 7)) << 3)];
        numacc[df] = mfma16(a, bv, numacc[df]);
      }
    }
    __builtin_amdgcn_s_setprio(0);
  }
  float den[4];
#pragma unroll
  for (int r = 0; r < 4; ++r) {
    float s = denacc[r];
    s += __shfl_xor(s, 1); s += __shfl_xor(s, 2);
    s += __shfl_xor(s, 4); s += __shfl_xor(s, 8);
    den[r] = s;
  }
  unsigned short* ab =
      attn + ((size_t)b * 4096 + lb * 128) * 1024 + h * 64;
#pragma unroll
  for (int df = 0; df < 4; ++df)
#pragma unroll
    for (int r = 0; r < 4; ++r)
      ab[(size_t)(w * 16 + 4 * g + r) * 1024 + df * 16 + li] =
          f2bf(numacc[df][r] / den[r]);
}

// ---------------------------------------------------------------------------
extern "C" void kernel_launch(void* const* d_in, const int* in_sizes, int n_in,
                              void* d_out, int out_size, void* d_ws, size_t ws_size,
                              hipStream_t stream) {
  (void)in_sizes; (void)n_in; (void)out_size; (void)ws_size;
  const float* x   = (const float*)d_in[0];
  const float* Wq  = (const float*)d_in[1];
  const float* bq  = (const float*)d_in[2];
  const float* Wk  = (const float*)d_in[3];
  const float* bk  = (const float*)d_in[4];
  const float* Wv  = (const float*)d_in[5];
  const float* bv  = (const float*)d_in[6];
  const float* Wo  = (const float*)d_in[7];
  const float* bo  = (const float*)d_in[8];
  const float* orf = (const float*)d_in[9];
  float* out = (float*)d_out;

  const size_t ND = (size_t)BB * LL * DD;   // 16,777,216
  char* base = (char*)d_ws;
  size_t off = 0;
  auto alloc = [&](size_t bytes) -> char* {
    char* p = base + off;
    off += (bytes + 255) & ~(size_t)255;
    return p;
  };
  unsigned short* wqbf   = (unsigned short*)alloc((size_t)DD * DD * 2);
  unsigned short* wkbf   = (unsigned short*)alloc((size_t)DD * DD * 2);
  unsigned short* wvbf   = (unsigned short*)alloc((size_t)DD * DD * 2);
  unsigned short* wobf   = (unsigned short*)alloc((size_t)DD * DD * 2);
  unsigned short* orfhi  = (unsigned short*)alloc((size_t)MMF * DK * 2);
  unsigned short* xbf    = (unsigned short*)alloc(ND * 2);   // aliased by pkv
  unsigned short* qhi    = (unsigned short*)alloc(ND * 2);
  unsigned short* qlo    = (unsigned short*)alloc(ND * 2);
  unsigned short* khi    = (unsigned short*)alloc(ND * 2);   // aliased by attnbf
  unsigned short* klo    = (unsigned short*)alloc(ND * 2);
  unsigned short* vtbuf  = (unsigned short*)alloc(ND * 2);
  float*          qnorms = (float*)alloc((size_t)64 * LL * 4);
  float*          knorms = (float*)alloc((size_t)64 * LL * 4);
  float*          pksum  = (float*)alloc((size_t)NSPLIT * 64 * MMF * 4);
  unsigned short* kvT    = (unsigned short*)alloc((size_t)64 * DK * MMF * 2);
  float*          ksg    = (float*)alloc((size_t)64 * MMF * 4);
  float*          pkv    = (float*)xbf;            // 33.5 MB, exact alias
  unsigned short* attnbf = khi;                    // khi dead after kv_mfma

  cvt_bf16<<<16384, 256, 0, stream>>>(x, xbf, (int)ND);
  cvt_bf16_w<<<dim3(1024, 4), 256, 0, stream>>>(Wq, Wk, Wv, Wo,
                                                wqbf, wkbf, wvbf, wobf);
  cvt_orf<<<64, 256, 0, stream>>>(orf, orfhi, MMF * DK);

  dim3 gg(64, 8);
  gemm_mfma<2><<<gg, 512, 0, stream>>>(xbf, wqbf, bq, (float*)0, qhi, qlo,
                                       qnorms, BB * LL, DD, DD);
  gemm_mfma<2><<<gg, 512, 0, stream>>>(xbf, wkbf, bk, (float*)0, khi, klo,
                                       knorms, BB * LL, DD, DD);
  gemm_mfma<1><<<gg, 512, 0, stream>>>(xbf, wvbf, bv, (float*)0, vtbuf,
                                       (unsigned short*)0, (float*)0,
                                       BB * LL, DD, DD);

  kv_mfma<<<dim3(64, NSPLIT), 256, 0, stream>>>(khi, klo, knorms, vtbuf,
                                                orfhi, pkv, pksum);
  reduce_parts<<<1024, 256, 0, stream>>>(pkv, kvT, pksum, ksg);
  qattn_mfma<<<dim3(64, 32), 512, 0, stream>>>(qhi, qlo, qnorms, orfhi,
                                               kvT, ksg, attnbf);

  gemm_mfma<0><<<gg, 512, 0, stream>>>(attnbf, wobf, bo, out, (unsigned short*)0,
                                       (unsigned short*)0, (float*)0,
                                       BB * LL, DD, DD);
}

// Round 15
// 295.111 us; speedup vs baseline: 1.0296x; 1.0296x over previous
//
#include <hip/hip_runtime.h>
#include <math.h>

// Problem constants
#define HH 16
#define BB 4
#define LL 4096
#define DD 1024
#define DK 64
#define MMF 256
#define EPSF 1e-6f
// orf scale: 64^-0.25 * log2(e)  (phi computed as exp2)
#define KSCALE (0.35355339059327373f * 1.4426950408889634f)
// norm scale: 1/(2*sqrt(64)) * log2(e)
#define NORMSCALE (0.0625f * 1.4426950408889634f)
#define NSPLIT 8
#define LCH (LL / NSPLIT)             // 512 rows of L per kv block

typedef __attribute__((ext_vector_type(8))) short bf16x8;
typedef __attribute__((ext_vector_type(4))) float f32x4;
typedef __attribute__((ext_vector_type(8))) unsigned short u16x8;

__device__ __forceinline__ unsigned short f2bf(float f) {
  union { float f; unsigned u; } v; v.f = f;
  unsigned r = v.u + 0x7FFF + ((v.u >> 16) & 1);   // RNE
  return (unsigned short)(r >> 16);
}
__device__ __forceinline__ float bf2f(unsigned short h) {
  union { unsigned u; float f; } v; v.u = ((unsigned)h) << 16;
  return v.f;
}
__device__ __forceinline__ f32x4 mfma16(bf16x8 a, bf16x8 b, f32x4 c) {
  return __builtin_amdgcn_mfma_f32_16x16x32_bf16(a, b, c, 0, 0, 0);
}
// single v_exp_f32 (exp2f routes through OCML's precise multi-inst path)
__device__ __forceinline__ float fexp2(float x) {
  return __builtin_amdgcn_exp2f(x);
}
// async global->LDS, 16B per lane; dst is wave-uniform base (lane x16 implicit)
__device__ __forceinline__ void gload16(const unsigned short* g, unsigned short* l) {
  __builtin_amdgcn_global_load_lds(
      (const __attribute__((address_space(1))) void*)g,
      (__attribute__((address_space(3))) void*)l, 16, 0, 0);
}
// T2 swizzle for 64-element bf16 rows (element-index xor)
#define SWZ(row, col) ((col) ^ (((row) & 7) << 3))

// ---------------------------------------------------------------------------
// fp32 -> bf16 conversion (n multiple of 4)
// ---------------------------------------------------------------------------
__global__ __launch_bounds__(256) void cvt_bf16(
    const float* __restrict__ src, unsigned short* __restrict__ dst, int n) {
  int i = (blockIdx.x * 256 + threadIdx.x) * 4;
  if (i < n) {
    float4 v = *(const float4*)&src[i];
    ushort4 o;
    o.x = f2bf(v.x); o.y = f2bf(v.y); o.z = f2bf(v.z); o.w = f2bf(v.w);
    *(ushort4*)&dst[i] = o;
  }
}

// fused 4-way weight conversion, grid (1024, 4)
__global__ __launch_bounds__(256) void cvt_bf16_w(
    const float* __restrict__ W0, const float* __restrict__ W1,
    const float* __restrict__ W2, const float* __restrict__ W3,
    unsigned short* __restrict__ D0, unsigned short* __restrict__ D1,
    unsigned short* __restrict__ D2, unsigned short* __restrict__ D3) {
  const float* s;
  unsigned short* d;
  switch (blockIdx.y) {
    case 0: s = W0; d = D0; break;
    case 1: s = W1; d = D1; break;
    case 2: s = W2; d = D2; break;
    default: s = W3; d = D3; break;
  }
  int i = (blockIdx.x * 256 + threadIdx.x) * 4;
  float4 v = *(const float4*)&s[i];
  ushort4 o;
  o.x = f2bf(v.x); o.y = f2bf(v.y); o.z = f2bf(v.z); o.w = f2bf(v.w);
  *(ushort4*)&d[i] = o;
}

// orf: scale by KSCALE (dk^-.25 * log2e), bf16
__global__ __launch_bounds__(256) void cvt_orf(
    const float* __restrict__ src, unsigned short* __restrict__ hi, int n) {
  int i = blockIdx.x * 256 + threadIdx.x;
  if (i < n) hi[i] = f2bf(src[i] * KSCALE);
}

// ---------------------------------------------------------------------------
// Shared GEMM core (r11-proven): 128x128 tile, BK=64, 4 waves (2x2), dbuf
// 64KB LDS, stage-next-first + counted vmcnt(8), 2 barriers/K-tile.
// Emitted via macro so the merged-QKV and output kernels share it exactly.
// Epilogue: per-wave LDS transpose (64x64 wave tile) -> coalesced stores.
// ---------------------------------------------------------------------------
#define GEMM_CORE(A_, W_, K_)                                                  \
  f32x4 acc[4][4] = {};                                                        \
  const int srow8 = lane >> 3;                                                 \
  const int scol  = ((lane & 7) ^ srow8) << 3;                                 \
  const unsigned short* Ag = (A_) + (size_t)(m0 + w * 32 + srow8) * (K_) + scol;\
  const unsigned short* Wg = (W_) + (size_t)(n0 + w * 32 + srow8) * (K_) + scol;\
  const int nt = (K_) >> 6;                                                    \
  _Pragma("unroll")                                                            \
  for (int j = 0; j < 4; ++j) {                                                \
    gload16(Ag + (size_t)j * 8 * (K_), S + (w * 32 + j * 8) * 64);             \
    gload16(Wg + (size_t)j * 8 * (K_), S + 8192 + (w * 32 + j * 8) * 64);      \
  }                                                                            \
  for (int t = 0; t < nt; ++t) {                                               \
    const int co = (t & 1) << 14;                                              \
    const int no = co ^ 16384;                                                 \
    if (t + 1 < nt) {                                                          \
      const int k1 = (t + 1) << 6;                                             \
      _Pragma("unroll")                                                        \
      for (int j = 0; j < 4; ++j) {                                            \
        gload16(Ag + (size_t)j * 8 * (K_) + k1, S + no + (w * 32 + j * 8) * 64);\
        gload16(Wg + (size_t)j * 8 * (K_) + k1,                                \
                S + no + 8192 + (w * 32 + j * 8) * 64);                        \
      }                                                                        \
      asm volatile("s_waitcnt vmcnt(8)" ::: "memory");                         \
    } else {                                                                   \
      asm volatile("s_waitcnt vmcnt(0)" ::: "memory");                         \
    }                                                                          \
    __builtin_amdgcn_s_barrier();                                              \
    const int sx = (li & 7) << 3;                                              \
    _Pragma("unroll")                                                          \
    for (int kk = 0; kk < 2; ++kk) {                                           \
      const int c = (kk * 32 + g * 8) ^ sx;                                    \
      bf16x8 af[4], bfr[4];                                                    \
      _Pragma("unroll")                                                        \
      for (int i = 0; i < 4; ++i)                                              \
        af[i] = *(const bf16x8*)&S[co + (wr * 64 + i * 16 + li) * 64 + c];     \
      _Pragma("unroll")                                                        \
      for (int j = 0; j < 4; ++j)                                              \
        bfr[j] = *(const bf16x8*)&S[co + 8192 + (wc * 64 + j * 16 + li) * 64 + c];\
      _Pragma("unroll")                                                        \
      for (int i = 0; i < 4; ++i)                                              \
        _Pragma("unroll")                                                      \
        for (int j = 0; j < 4; ++j)                                            \
          acc[i][j] = mfma16(af[i], bfr[j], acc[i][j]);                        \
    }                                                                          \
    asm volatile("s_waitcnt lgkmcnt(0)" ::: "memory");                         \
    __builtin_amdgcn_s_barrier();                                              \
  }

// MODE-2 epilogue body (hi/lo bf16 + norms), uses acc/ep/lane/g/li
#define EPI_MODE2(C1_, C2_, Cn_, biasp_)                                       \
  _Pragma("unroll")                                                            \
  for (int jh = 0; jh < 2; ++jh) {                                             \
    _Pragma("unroll")                                                          \
    for (int i2 = 0; i2 < 2; ++i2) {                                           \
      const int i = jh * 2 + i2;                                               \
      _Pragma("unroll")                                                        \
      for (int j = 0; j < 4; ++j) {                                            \
        const float bz = (biasp_)[j * 16 + li];                                \
        _Pragma("unroll")                                                      \
        for (int r = 0; r < 4; ++r)                                            \
          ep[(i2 * 16 + 4 * g + r) * 68 + j * 16 + li] = acc[i][j][r] + bz;    \
      }                                                                        \
    }                                                                          \
    const int rrow = lane >> 3, cc = lane & 7;                                 \
    _Pragma("unroll")                                                          \
    for (int p = 0; p < 4; ++p) {                                              \
      const int row = p * 8 + rrow;                                            \
      float v[8];                                                              \
      *(f32x4*)&v[0] = *(const f32x4*)&ep[row * 68 + cc * 8];                  \
      *(f32x4*)&v[4] = *(const f32x4*)&ep[row * 68 + cc * 8 + 4];              \
      float np = 0.f;                                                          \
      u16x8 hv, lv;                                                            \
      _Pragma("unroll")                                                        \
      for (int e = 0; e < 8; ++e) {                                            \
        float vv = v[e];                                                       \
        np += vv * vv;                                                         \
        unsigned short h2 = f2bf(vv);                                          \
        hv[e] = h2;                                                            \
        lv[e] = f2bf(vv - bf2f(h2));                                           \
      }                                                                        \
      const int lg = (rbase + jh * 32 + row) & 4095;                           \
      const size_t rowb = (size_t)(b * 16 + head) * 4096 + lg;                 \
      *(u16x8*)&(C1_)[rowb * 64 + cc * 8] = hv;                                \
      *(u16x8*)&(C2_)[rowb * 64 + cc * 8] = lv;                                \
      np += __shfl_xor(np, 1);                                                 \
      np += __shfl_xor(np, 2);                                                 \
      np += __shfl_xor(np, 4);                                                 \
      if (cc == 0) (Cn_)[rowb] = np * NORMSCALE;                               \
    }                                                                          \
  }

// ---------------------------------------------------------------------------
// Merged Q/K/V GEMM: grid (128, 24) = 3072 blocks. Per XCD: seg-major order
// (W-seg 2MB L2-resident), then 16 m-panels x 8 n-panels.
// seg 0 -> Q (hi/lo + norms), seg 1 -> K (hi/lo + norms), seg 2 -> V^T bf16.
// ---------------------------------------------------------------------------
__global__ __launch_bounds__(256) void gemm_qkv(
    const unsigned short* __restrict__ xbf,
    const unsigned short* __restrict__ wq, const unsigned short* __restrict__ wk,
    const unsigned short* __restrict__ wv,
    const float* __restrict__ bq, const float* __restrict__ bk,
    const float* __restrict__ bv,
    unsigned short* __restrict__ qhi, unsigned short* __restrict__ qlo,
    float* __restrict__ qnorms,
    unsigned short* __restrict__ khi, unsigned short* __restrict__ klo,
    float* __restrict__ knorms,
    unsigned short* __restrict__ vt) {
  __shared__ __align__(16) char smem[65536];
  unsigned short* S = (unsigned short*)smem;
  const int tid = threadIdx.x, lane = tid & 63;
  const int w = tid >> 6, wr = w >> 1, wc = w & 1;
  const int g = lane >> 4, li = lane & 15;
  const int flat = blockIdx.y * gridDim.x + blockIdx.x;   // 0..3071
  const int xcd = flat & 7, loc = flat >> 3;              // 0..383
  const int seg = loc >> 7;                               // 0..2
  const int idx = loc & 127;                              // 16 m x 8 n
  const int m0 = (xcd * 16 + (idx >> 3)) * 128;
  const int n0 = (idx & 7) * 128;                         // within seg
  const unsigned short* W = seg == 0 ? wq : seg == 1 ? wk : wv;
  const float* bias = seg == 0 ? bq : seg == 1 ? bk : bv;

  GEMM_CORE(xbf, W, DD)

  float* ep = (float*)smem + w * (32 * 68);
  const int head = (n0 + wc * 64) >> 6;
  const int rbase = m0 + wr * 64;
  const int b = rbase >> 12;
  const float* biasp = bias + n0 + wc * 64;

  if (seg == 0) {
    EPI_MODE2(qhi, qlo, qnorms, biasp)
  } else if (seg == 1) {
    EPI_MODE2(khi, klo, knorms, biasp)
  } else {
    // MODE 1: bf16 transposed Ct[(b*16+head)*64 + d][4096]
#pragma unroll
    for (int jh = 0; jh < 2; ++jh) {
#pragma unroll
      for (int i = 0; i < 4; ++i)
#pragma unroll
        for (int j2 = 0; j2 < 2; ++j2) {
          const int j = jh * 2 + j2;
          const float bz = biasp[j * 16 + li];
          f32x4 t;
          t[0] = acc[i][j][0] + bz; t[1] = acc[i][j][1] + bz;
          t[2] = acc[i][j][2] + bz; t[3] = acc[i][j][3] + bz;
          *(f32x4*)&ep[(j2 * 16 + li) * 68 + i * 16 + 4 * g] = t;
        }
      const int rd = lane >> 3, cc = lane & 7;
#pragma unroll
      for (int p = 0; p < 4; ++p) {
        const int dl = p * 8 + rd;
        float v[8];
        *(f32x4*)&v[0] = *(const f32x4*)&ep[dl * 68 + cc * 8];
        *(f32x4*)&v[4] = *(const f32x4*)&ep[dl * 68 + cc * 8 + 4];
        u16x8 hv;
#pragma unroll
        for (int e = 0; e < 8; ++e) hv[e] = f2bf(v[e]);
        const int dh = jh * 32 + dl;
        const int lg = rbase & 4095;
        *(u16x8*)&vt[((size_t)(b * 16 + head) * 64 + dh) * 4096 + lg + cc * 8] = hv;
      }
    }
  }
}

// ---------------------------------------------------------------------------
// Output GEMM (fp32 row-major): C = attn @ Wo^T + bo. grid (128, 8).
// ---------------------------------------------------------------------------
__global__ __launch_bounds__(256) void gemm_out(
    const unsigned short* __restrict__ A, const unsigned short* __restrict__ Wo,
    const float* __restrict__ bias, float* __restrict__ Cf) {
  __shared__ __align__(16) char smem[65536];
  unsigned short* S = (unsigned short*)smem;
  const int tid = threadIdx.x, lane = tid & 63;
  const int w = tid >> 6, wr = w >> 1, wc = w & 1;
  const int g = lane >> 4, li = lane & 15;
  const int flat = blockIdx.y * gridDim.x + blockIdx.x;   // 0..1023
  const int xcd = flat & 7, loc = flat >> 3;
  const int m0 = ((xcd << 4) + (loc & 15)) * 128;
  const int n0 = (loc >> 4) * 128;

  GEMM_CORE(A, Wo, DD)

  float* ep = (float*)smem + w * (32 * 68);
  const int rbase = m0 + wr * 64;
#pragma unroll
  for (int jh = 0; jh < 2; ++jh) {
#pragma unroll
    for (int i2 = 0; i2 < 2; ++i2) {
      const int i = jh * 2 + i2;
#pragma unroll
      for (int j = 0; j < 4; ++j) {
        const float bz = bias[n0 + wc * 64 + j * 16 + li];
#pragma unroll
        for (int r = 0; r < 4; ++r)
          ep[(i2 * 16 + 4 * g + r) * 68 + j * 16 + li] = acc[i][j][r] + bz;
      }
    }
    const int rrow = lane >> 4, cc = lane & 15;
#pragma unroll
    for (int p = 0; p < 8; ++p) {
      const int row = p * 4 + rrow;
      f32x4 v = *(const f32x4*)&ep[row * 68 + cc * 4];
      *(f32x4*)&Cf[(size_t)(rbase + jh * 32 + row) * 1024 + n0 + wc * 64 + cc * 4] = v;
    }
  }
}

// ---------------------------------------------------------------------------
// kv + ksum. grid (64 bh, NSPLIT), 256 thr / 4 waves. 2-TERM proj split:
// oh*(khi + klo). phi via single v_exp_f32. (r11 structure, unchanged)
// ---------------------------------------------------------------------------
__global__ __launch_bounds__(256, 2) void kv_mfma(
    const unsigned short* __restrict__ khi, const unsigned short* __restrict__ klo,
    const float* __restrict__ knorms, const unsigned short* __restrict__ vt,
    const unsigned short* __restrict__ orfhi,
    float* __restrict__ pkv, float* __restrict__ pksum) {
  __shared__ __align__(16) unsigned short KsHi[64 * 64], KsLo[64 * 64];
  __shared__ __align__(16) unsigned short VT[64 * 64], KphiT[64 * 64];
  __shared__ float ns[64];
  const int tid = threadIdx.x, lane = tid & 63, w = tid >> 6;
  const int g = lane >> 4, li = lane & 15;
  const int bh = blockIdx.x, sp = blockIdx.y;
  const int srow8 = lane >> 3;
  const int scol  = ((lane & 7) ^ srow8) << 3;
  const int sx = (li & 7) << 3;

  bf16x8 oh[4][2];
#pragma unroll
  for (int p = 0; p < 4; ++p)
#pragma unroll
    for (int kk = 0; kk < 2; ++kk)
      oh[p][kk] = *(const bf16x8*)
          &orfhi[(size_t)(p * 64 + w * 16 + li) * 64 + kk * 32 + g * 8];

  f32x4 kvacc[4][4] = {};
  float ksacc[4][4] = {};

  for (int c = 0; c < LCH / 64; ++c) {
    const int l0 = sp * LCH + c * 64;
    __syncthreads();
    {
      const size_t kb = ((size_t)bh * 4096 + l0 + w * 16 + srow8) * 64 + scol;
      gload16(khi + kb, &KsHi[(w * 16) * 64]);
      gload16(khi + kb + 8 * 64, &KsHi[(w * 16 + 8) * 64]);
      gload16(klo + kb, &KsLo[(w * 16) * 64]);
      gload16(klo + kb + 8 * 64, &KsLo[(w * 16 + 8) * 64]);
      const size_t vb = ((size_t)bh * 64 + w * 16 + srow8) * 4096 + l0 + scol;
      gload16(vt + vb, &VT[(w * 16) * 64]);
      gload16(vt + vb + (size_t)8 * 4096, &VT[(w * 16 + 8) * 64]);
      if (tid < 64) ns[tid] = knorms[(size_t)bh * 4096 + l0 + tid];
    }
    __syncthreads();

#pragma unroll
    for (int p = 0; p < 4; ++p) {
      f32x4 pr[4] = {};
      __builtin_amdgcn_s_setprio(1);
#pragma unroll
      for (int kk = 0; kk < 2; ++kk) {
        const int cx = (kk * 32 + g * 8) ^ sx;
#pragma unroll
        for (int lf = 0; lf < 4; ++lf) {
          const bf16x8 bh2 = *(const bf16x8*)&KsHi[(lf * 16 + li) * 64 + cx];
          const bf16x8 bl2 = *(const bf16x8*)&KsLo[(lf * 16 + li) * 64 + cx];
          pr[lf] = mfma16(oh[p][kk], bh2, pr[lf]);
          pr[lf] = mfma16(oh[p][kk], bl2, pr[lf]);
        }
      }
      __builtin_amdgcn_s_setprio(0);
#pragma unroll
      for (int lf = 0; lf < 4; ++lf) {
        const float nrm = ns[lf * 16 + li];
#pragma unroll
        for (int r = 0; r < 4; ++r) {
          float phi = fexp2(pr[lf][r] - nrm) + EPSF;
          ksacc[p][r] += phi;
          const int row = w * 16 + 4 * g + r;
          KphiT[row * 64 + SWZ(row, lf * 16 + li)] = f2bf(phi);
        }
      }
      __builtin_amdgcn_s_setprio(1);
#pragma unroll
      for (int kk = 0; kk < 2; ++kk) {
        const int cx = (kk * 32 + g * 8) ^ sx;
        const bf16x8 a = *(const bf16x8*)&KphiT[(w * 16 + li) * 64 + cx];
#pragma unroll
        for (int df = 0; df < 4; ++df) {
          const bf16x8 bv = *(const bf16x8*)&VT[(df * 16 + li) * 64 + cx];
          kvacc[p][df] = mfma16(a, bv, kvacc[p][df]);
        }
      }
      __builtin_amdgcn_s_setprio(0);
    }
  }
  float* kvo = pkv + ((size_t)sp * 64 + bh) * (MMF * DK);
#pragma unroll
  for (int p = 0; p < 4; ++p)
#pragma unroll
    for (int df = 0; df < 4; ++df)
#pragma unroll
      for (int r = 0; r < 4; ++r)
        kvo[(p * 64 + w * 16 + 4 * g + r) * DK + df * 16 + li] = kvacc[p][df][r];

  float* kso = pksum + ((size_t)sp * 64 + bh) * MMF;
#pragma unroll
  for (int p = 0; p < 4; ++p)
#pragma unroll
    for (int r = 0; r < 4; ++r) {
      float s = ksacc[p][r];
      s += __shfl_xor(s, 1); s += __shfl_xor(s, 2);
      s += __shfl_xor(s, 4); s += __shfl_xor(s, 8);
      if (li == 0) kso[p * 64 + w * 16 + 4 * g + r] = s;
    }
}

// ---------------------------------------------------------------------------
// reduce partials; emit kv TRANSPOSED bf16 kvT[bh][d][m] + ksum fp32
// ---------------------------------------------------------------------------
__global__ __launch_bounds__(256) void reduce_parts(
    const float* __restrict__ pkv, unsigned short* __restrict__ kvT,
    const float* __restrict__ pks, float* __restrict__ ksg) {
  const int id = blockIdx.x * 256 + threadIdx.x;   // grid 1024 -> 262144
  {
    const int bh = id >> 12, rest = id & 4095;
    const int m0 = (rest >> 6) << 2, d = rest & 63;
    float s0 = 0.f, s1 = 0.f, s2 = 0.f, s3 = 0.f;
#pragma unroll
    for (int sp = 0; sp < NSPLIT; ++sp) {
      const float* p = pkv + (size_t)(sp * 64 + bh) * (MMF * DK) + d;
      s0 += p[(m0 + 0) * DK]; s1 += p[(m0 + 1) * DK];
      s2 += p[(m0 + 2) * DK]; s3 += p[(m0 + 3) * DK];
    }
    ushort4 o;
    o.x = f2bf(s0); o.y = f2bf(s1); o.z = f2bf(s2); o.w = f2bf(s3);
    *(ushort4*)&kvT[((size_t)bh * DK + d) * MMF + m0] = o;
  }
  if (id < 4096) {
    float4 s = {0.f, 0.f, 0.f, 0.f};
#pragma unroll
    for (int sp = 0; sp < NSPLIT; ++sp) {
      float4 v = *(const float4*)&pks[(size_t)sp * 64 * MMF + id * 4];
      s.x += v.x; s.y += v.y; s.z += v.z; s.w += v.w;
    }
    *(float4*)&ksg[id * 4] = s;
  }
}

// ---------------------------------------------------------------------------
// q_phi + num/den -> attn (bf16). grid (64 bh, 32 l-blocks), 512 threads.
// (r11 structure, unchanged)
// ---------------------------------------------------------------------------
__global__ __launch_bounds__(512, 4) void qattn_mfma(
    const unsigned short* __restrict__ qhi, const unsigned short* __restrict__ qlo,
    const float* __restrict__ qnorms,
    const unsigned short* __restrict__ orfhi,
    const unsigned short* __restrict__ kvT, const float* __restrict__ ksg,
    unsigned short* __restrict__ attn) {
  __shared__ __align__(16) unsigned short OHi[256 * 64];    // 32 KB
  __shared__ __align__(16) unsigned short KvTs[64 * 256];   // 32 KB
  __shared__ __align__(16) unsigned short Qphi[8][16 * 64]; // 16 KB
  const int tid = threadIdx.x, lane = tid & 63, w = tid >> 6;
  const int g = lane >> 4, li = lane & 15;
  const int bh = blockIdx.x, lb = blockIdx.y;
  const int b = bh >> 4, h = bh & 15;
  const int srow8 = lane >> 3;
  const int scol  = ((lane & 7) ^ srow8) << 3;
  const int sx = (li & 7) << 3;

#pragma unroll
  for (int q = 0; q < 4; ++q) {
    const size_t o = (size_t)(w * 32 + q * 8 + srow8) * 64 + scol;
    gload16(orfhi + o, &OHi[(w * 32 + q * 8) * 64]);
  }
  {
    const int srow2 = lane >> 5;
#pragma unroll
    for (int q = 0; q < 4; ++q) {
      const int d0 = w * 8 + q * 2, dr = d0 + srow2;
      gload16(kvT + ((size_t)bh * DK + dr) * MMF + (((lane & 31) ^ (dr & 7)) << 3),
              &KvTs[d0 * 256]);
    }
  }

  float ksr[4][4];
#pragma unroll
  for (int p = 0; p < 4; ++p)
#pragma unroll
    for (int mf = 0; mf < 4; ++mf)
      ksr[p][mf] = ksg[(size_t)bh * MMF + p * 64 + mf * 16 + li];
  const float4 nr =
      *(const float4*)&qnorms[(size_t)bh * 4096 + lb * 128 + w * 16 + 4 * g];
  bf16x8 qh[2], ql[2];
  {
    const size_t qr = ((size_t)bh * 4096 + lb * 128 + w * 16 + li) * 64 + g * 8;
    qh[0] = *(const bf16x8*)&qhi[qr];
    qh[1] = *(const bf16x8*)&qhi[qr + 32];
    ql[0] = *(const bf16x8*)&qlo[qr];
    ql[1] = *(const bf16x8*)&qlo[qr + 32];
  }
  __syncthreads();

  f32x4 numacc[4] = {};
  float denacc[4] = {};

#pragma unroll
  for (int p = 0; p < 4; ++p) {
    f32x4 pr[4] = {};
    __builtin_amdgcn_s_setprio(1);
#pragma unroll
    for (int kk = 0; kk < 2; ++kk) {
      const int cx = (kk * 32 + g * 8) ^ sx;
#pragma unroll
      for (int mf = 0; mf < 4; ++mf) {
        const int row = p * 64 + mf * 16 + li;
        const bf16x8 bh2 = *(const bf16x8*)&OHi[row * 64 + cx];
        pr[mf] = mfma16(qh[kk], bh2, pr[mf]);
        pr[mf] = mfma16(ql[kk], bh2, pr[mf]);
      }
    }
    __builtin_amdgcn_s_setprio(0);
#pragma unroll
    for (int mf = 0; mf < 4; ++mf) {
      const float ks = ksr[p][mf];
#pragma unroll
      for (int r = 0; r < 4; ++r) {
        float phi = fexp2(pr[mf][r] - nr[r]) + EPSF;
        denacc[r] += phi * ks;
        const int row = 4 * g + r;
        Qphi[w][row * 64 + SWZ(row, mf * 16 + li)] = f2bf(phi);
      }
    }
    __builtin_amdgcn_s_setprio(1);
#pragma unroll
    for (int kk = 0; kk < 2; ++kk) {
      const int cx = (kk * 32 + g * 8) ^ sx;
      const bf16x8 a = *(const bf16x8*)&Qphi[w][li * 64 + cx];
#pragma unroll
      for (int df = 0; df < 4; ++df) {
        const bf16x8 bv = *(const bf16x8*)
            &KvTs[(df * 16 + li) * 256 + (((p * 8 + kk * 4 + g) ^ (li & 7)) << 3)];
        numacc[df] = mfma16(a, bv, numacc[df]);
      }
    }
    __builtin_amdgcn_s_setprio(0);
  }
  float den[4];
#pragma unroll
  for (int r = 0; r < 4; ++r) {
    float s = denacc[r];
    s += __shfl_xor(s, 1); s += __shfl_xor(s, 2);
    s += __shfl_xor(s, 4); s += __shfl_xor(s, 8);
    den[r] = s;
  }
  unsigned short* ab =
      attn + ((size_t)b * 4096 + lb * 128) * 1024 + h * 64;
#pragma unroll
  for (int df = 0; df < 4; ++df)
#pragma unroll
    for (int r = 0; r < 4; ++r)
      ab[(size_t)(w * 16 + 4 * g + r) * 1024 + df * 16 + li] =
          f2bf(numacc[df][r] / den[r]);
}

// ---------------------------------------------------------------------------
extern "C" void kernel_launch(void* const* d_in, const int* in_sizes, int n_in,
                              void* d_out, int out_size, void* d_ws, size_t ws_size,
                              hipStream_t stream) {
  (void)in_sizes; (void)n_in; (void)out_size; (void)ws_size;
  const float* x   = (const float*)d_in[0];
  const float* Wq  = (const float*)d_in[1];
  const float* bq  = (const float*)d_in[2];
  const float* Wk  = (const float*)d_in[3];
  const float* bk  = (const float*)d_in[4];
  const float* Wv  = (const float*)d_in[5];
  const float* bv  = (const float*)d_in[6];
  const float* Wo  = (const float*)d_in[7];
  const float* bo  = (const float*)d_in[8];
  const float* orf = (const float*)d_in[9];
  float* out = (float*)d_out;

  const size_t ND = (size_t)BB * LL * DD;   // 16,777,216
  char* base = (char*)d_ws;
  size_t off = 0;
  auto alloc = [&](size_t bytes) -> char* {
    char* p = base + off;
    off += (bytes + 255) & ~(size_t)255;
    return p;
  };
  unsigned short* wqbf   = (unsigned short*)alloc((size_t)DD * DD * 2);
  unsigned short* wkbf   = (unsigned short*)alloc((size_t)DD * DD * 2);
  unsigned short* wvbf   = (unsigned short*)alloc((size_t)DD * DD * 2);
  unsigned short* wobf   = (unsigned short*)alloc((size_t)DD * DD * 2);
  unsigned short* orfhi  = (unsigned short*)alloc((size_t)MMF * DK * 2);
  unsigned short* xbf    = (unsigned short*)alloc(ND * 2);   // aliased by pkv
  unsigned short* qhi    = (unsigned short*)alloc(ND * 2);
  unsigned short* qlo    = (unsigned short*)alloc(ND * 2);
  unsigned short* khi    = (unsigned short*)alloc(ND * 2);   // aliased by attnbf
  unsigned short* klo    = (unsigned short*)alloc(ND * 2);
  unsigned short* vtbuf  = (unsigned short*)alloc(ND * 2);
  float*          qnorms = (float*)alloc((size_t)64 * LL * 4);
  float*          knorms = (float*)alloc((size_t)64 * LL * 4);
  float*          pksum  = (float*)alloc((size_t)NSPLIT * 64 * MMF * 4);
  unsigned short* kvT    = (unsigned short*)alloc((size_t)64 * DK * MMF * 2);
  float*          ksg    = (float*)alloc((size_t)64 * MMF * 4);
  float*          pkv    = (float*)xbf;            // 33.5 MB, exact alias
  unsigned short* attnbf = khi;                    // khi dead after kv_mfma

  cvt_bf16<<<16384, 256, 0, stream>>>(x, xbf, (int)ND);
  cvt_bf16_w<<<dim3(1024, 4), 256, 0, stream>>>(Wq, Wk, Wv, Wo,
                                                wqbf, wkbf, wvbf, wobf);
  cvt_orf<<<64, 256, 0, stream>>>(orf, orfhi, MMF * DK);

  gemm_qkv<<<dim3(128, 24), 256, 0, stream>>>(
      xbf, wqbf, wkbf, wvbf, bq, bk, bv,
      qhi, qlo, qnorms, khi, klo, knorms, vtbuf);

  kv_mfma<<<dim3(64, NSPLIT), 256, 0, stream>>>(khi, klo, knorms, vtbuf,
                                                orfhi, pkv, pksum);
  reduce_parts<<<1024, 256, 0, stream>>>(pkv, kvT, pksum, ksg);
  qattn_mfma<<<dim3(64, 32), 512, 0, stream>>>(qhi, qlo, qnorms, orfhi,
                                               kvT, ksg, attnbf);

  gemm_out<<<dim3(128, 8), 256, 0, stream>>>(attnbf, wobf, bo, out);
}

// Round 16
// 285.433 us; speedup vs baseline: 1.0646x; 1.0339x over previous
//
#include <hip/hip_runtime.h>
#include <math.h>

// Problem constants
#define HH 16
#define BB 4
#define LL 4096
#define DD 1024
#define DK 64
#define MMF 256
#define EPSF 1e-6f
// orf scale: 64^-0.25 * log2(e)  (phi computed as exp2)
#define KSCALE (0.35355339059327373f * 1.4426950408889634f)
// norm scale: 1/(2*sqrt(64)) * log2(e)
#define NORMSCALE (0.0625f * 1.4426950408889634f)
#define NSPLIT 8
#define LCH (LL / NSPLIT)             // 512 rows of L per kv block

typedef __attribute__((ext_vector_type(8))) short bf16x8;
typedef __attribute__((ext_vector_type(4))) float f32x4;
typedef __attribute__((ext_vector_type(8))) unsigned short u16x8;

__device__ __forceinline__ unsigned short f2bf(float f) {
  union { float f; unsigned u; } v; v.f = f;
  unsigned r = v.u + 0x7FFF + ((v.u >> 16) & 1);   // RNE
  return (unsigned short)(r >> 16);
}
__device__ __forceinline__ float bf2f(unsigned short h) {
  union { unsigned u; float f; } v; v.u = ((unsigned)h) << 16;
  return v.f;
}
__device__ __forceinline__ f32x4 mfma16(bf16x8 a, bf16x8 b, f32x4 c) {
  return __builtin_amdgcn_mfma_f32_16x16x32_bf16(a, b, c, 0, 0, 0);
}
// single v_exp_f32 (exp2f routes through OCML's precise multi-inst path)
__device__ __forceinline__ float fexp2(float x) {
  return __builtin_amdgcn_exp2f(x);
}
// async global->LDS, 16B per lane; dst is wave-uniform base (lane x16 implicit)
__device__ __forceinline__ void gload16(const unsigned short* g, unsigned short* l) {
  __builtin_amdgcn_global_load_lds(
      (const __attribute__((address_space(1))) void*)g,
      (__attribute__((address_space(3))) void*)l, 16, 0, 0);
}
// T2 swizzle for 64-element bf16 rows (element-index xor)
#define SWZ(row, col) ((col) ^ (((row) & 7) << 3))

// ---------------------------------------------------------------------------
// merged fp32->bf16 conversion: x (16384 blks) + 4 weights (1024 each) +
// orf (16 blks, scaled). One dispatch, 20496 blocks.
// ---------------------------------------------------------------------------
__global__ __launch_bounds__(256) void cvt_all(
    const float* __restrict__ x,
    const float* __restrict__ Wq, const float* __restrict__ Wk,
    const float* __restrict__ Wv, const float* __restrict__ Wo,
    const float* __restrict__ orf,
    unsigned short* __restrict__ xbf,
    unsigned short* __restrict__ wqbf, unsigned short* __restrict__ wkbf,
    unsigned short* __restrict__ wvbf, unsigned short* __restrict__ wobf,
    unsigned short* __restrict__ orfhi) {
  const int bid = blockIdx.x;
  const float* s;
  unsigned short* d;
  int base;
  float scale = 1.0f;
  if (bid < 16384)      { s = x;   d = xbf;   base = bid; }
  else if (bid < 17408) { s = Wq;  d = wqbf;  base = bid - 16384; }
  else if (bid < 18432) { s = Wk;  d = wkbf;  base = bid - 17408; }
  else if (bid < 19456) { s = Wv;  d = wvbf;  base = bid - 18432; }
  else if (bid < 20480) { s = Wo;  d = wobf;  base = bid - 19456; }
  else                  { s = orf; d = orfhi; base = bid - 20480; scale = KSCALE; }
  const int i = (base * 256 + threadIdx.x) * 4;
  float4 v = *(const float4*)&s[i];
  ushort4 o;
  o.x = f2bf(v.x * scale); o.y = f2bf(v.y * scale);
  o.z = f2bf(v.z * scale); o.w = f2bf(v.w * scale);
  *(ushort4*)&d[i] = o;
}

// ---------------------------------------------------------------------------
// Shared GEMM core (r11-proven): 128x128 tile, BK=64, 4 waves (2x2), dbuf
// 64KB LDS, stage-next-first + counted vmcnt(8), 2 barriers/K-tile.
// ---------------------------------------------------------------------------
#define GEMM_CORE(A_, W_, K_)                                                  \
  f32x4 acc[4][4] = {};                                                        \
  const int srow8 = lane >> 3;                                                 \
  const int scol  = ((lane & 7) ^ srow8) << 3;                                 \
  const unsigned short* Ag = (A_) + (size_t)(m0 + w * 32 + srow8) * (K_) + scol;\
  const unsigned short* Wg = (W_) + (size_t)(n0 + w * 32 + srow8) * (K_) + scol;\
  const int nt = (K_) >> 6;                                                    \
  _Pragma("unroll")                                                            \
  for (int j = 0; j < 4; ++j) {                                                \
    gload16(Ag + (size_t)j * 8 * (K_), S + (w * 32 + j * 8) * 64);             \
    gload16(Wg + (size_t)j * 8 * (K_), S + 8192 + (w * 32 + j * 8) * 64);      \
  }                                                                            \
  for (int t = 0; t < nt; ++t) {                                               \
    const int co = (t & 1) << 14;                                              \
    const int no = co ^ 16384;                                                 \
    if (t + 1 < nt) {                                                          \
      const int k1 = (t + 1) << 6;                                             \
      _Pragma("unroll")                                                        \
      for (int j = 0; j < 4; ++j) {                                            \
        gload16(Ag + (size_t)j * 8 * (K_) + k1, S + no + (w * 32 + j * 8) * 64);\
        gload16(Wg + (size_t)j * 8 * (K_) + k1,                                \
                S + no + 8192 + (w * 32 + j * 8) * 64);                        \
      }                                                                        \
      asm volatile("s_waitcnt vmcnt(8)" ::: "memory");                         \
    } else {                                                                   \
      asm volatile("s_waitcnt vmcnt(0)" ::: "memory");                         \
    }                                                                          \
    __builtin_amdgcn_s_barrier();                                              \
    const int sx = (li & 7) << 3;                                              \
    _Pragma("unroll")                                                          \
    for (int kk = 0; kk < 2; ++kk) {                                           \
      const int c = (kk * 32 + g * 8) ^ sx;                                    \
      bf16x8 af[4], bfr[4];                                                    \
      _Pragma("unroll")                                                        \
      for (int i = 0; i < 4; ++i)                                              \
        af[i] = *(const bf16x8*)&S[co + (wr * 64 + i * 16 + li) * 64 + c];     \
      _Pragma("unroll")                                                        \
      for (int j = 0; j < 4; ++j)                                              \
        bfr[j] = *(const bf16x8*)&S[co + 8192 + (wc * 64 + j * 16 + li) * 64 + c];\
      _Pragma("unroll")                                                        \
      for (int i = 0; i < 4; ++i)                                              \
        _Pragma("unroll")                                                      \
        for (int j = 0; j < 4; ++j)                                            \
          acc[i][j] = mfma16(af[i], bfr[j], acc[i][j]);                        \
    }                                                                          \
    asm volatile("s_waitcnt lgkmcnt(0)" ::: "memory");                         \
    __builtin_amdgcn_s_barrier();                                              \
  }

// K-path epilogue: hi/lo bf16 + norms
#define EPI_MODE2(C1_, C2_, Cn_, biasp_)                                       \
  _Pragma("unroll")                                                            \
  for (int jh = 0; jh < 2; ++jh) {                                             \
    _Pragma("unroll")                                                          \
    for (int i2 = 0; i2 < 2; ++i2) {                                           \
      const int i = jh * 2 + i2;                                               \
      _Pragma("unroll")                                                        \
      for (int j = 0; j < 4; ++j) {                                            \
        const float bz = (biasp_)[j * 16 + li];                                \
        _Pragma("unroll")                                                      \
        for (int r = 0; r < 4; ++r)                                            \
          ep[(i2 * 16 + 4 * g + r) * 68 + j * 16 + li] = acc[i][j][r] + bz;    \
      }                                                                        \
    }                                                                          \
    const int rrow = lane >> 3, cc = lane & 7;                                 \
    _Pragma("unroll")                                                          \
    for (int p = 0; p < 4; ++p) {                                              \
      const int row = p * 8 + rrow;                                            \
      float v[8];                                                              \
      *(f32x4*)&v[0] = *(const f32x4*)&ep[row * 68 + cc * 8];                  \
      *(f32x4*)&v[4] = *(const f32x4*)&ep[row * 68 + cc * 8 + 4];              \
      float np = 0.f;                                                          \
      u16x8 hv, lv;                                                            \
      _Pragma("unroll")                                                        \
      for (int e = 0; e < 8; ++e) {                                            \
        float vv = v[e];                                                       \
        np += vv * vv;                                                         \
        unsigned short h2 = f2bf(vv);                                          \
        hv[e] = h2;                                                            \
        lv[e] = f2bf(vv - bf2f(h2));                                           \
      }                                                                        \
      const int lg = (rbase + jh * 32 + row) & 4095;                           \
      const size_t rowb = (size_t)(b * 16 + head) * 4096 + lg;                 \
      *(u16x8*)&(C1_)[rowb * 64 + cc * 8] = hv;                                \
      *(u16x8*)&(C2_)[rowb * 64 + cc * 8] = lv;                                \
      np += __shfl_xor(np, 1);                                                 \
      np += __shfl_xor(np, 2);                                                 \
      np += __shfl_xor(np, 4);                                                 \
      if (cc == 0) (Cn_)[rowb] = np * NORMSCALE;                               \
    }                                                                          \
  }

// Q-path epilogue: single bf16 + norms (lo dropped — q-side phi error
// ratio-cancels in num/den; r5 evidence)
#define EPI_Q(C1_, Cn_, biasp_)                                                \
  _Pragma("unroll")                                                            \
  for (int jh = 0; jh < 2; ++jh) {                                             \
    _Pragma("unroll")                                                          \
    for (int i2 = 0; i2 < 2; ++i2) {                                           \
      const int i = jh * 2 + i2;                                               \
      _Pragma("unroll")                                                        \
      for (int j = 0; j < 4; ++j) {                                            \
        const float bz = (biasp_)[j * 16 + li];                                \
        _Pragma("unroll")                                                      \
        for (int r = 0; r < 4; ++r)                                            \
          ep[(i2 * 16 + 4 * g + r) * 68 + j * 16 + li] = acc[i][j][r] + bz;    \
      }                                                                        \
    }                                                                          \
    const int rrow = lane >> 3, cc = lane & 7;                                 \
    _Pragma("unroll")                                                          \
    for (int p = 0; p < 4; ++p) {                                              \
      const int row = p * 8 + rrow;                                            \
      float v[8];                                                              \
      *(f32x4*)&v[0] = *(const f32x4*)&ep[row * 68 + cc * 8];                  \
      *(f32x4*)&v[4] = *(const f32x4*)&ep[row * 68 + cc * 8 + 4];              \
      float np = 0.f;                                                          \
      u16x8 hv;                                                                \
      _Pragma("unroll")                                                        \
      for (int e = 0; e < 8; ++e) {                                            \
        float vv = v[e];                                                       \
        np += vv * vv;                                                         \
        hv[e] = f2bf(vv);                                                      \
      }                                                                        \
      const int lg = (rbase + jh * 32 + row) & 4095;                           \
      const size_t rowb = (size_t)(b * 16 + head) * 4096 + lg;                 \
      *(u16x8*)&(C1_)[rowb * 64 + cc * 8] = hv;                                \
      np += __shfl_xor(np, 1);                                                 \
      np += __shfl_xor(np, 2);                                                 \
      np += __shfl_xor(np, 4);                                                 \
      if (cc == 0) (Cn_)[rowb] = np * NORMSCALE;                               \
    }                                                                          \
  }

// ---------------------------------------------------------------------------
// Merged Q/K/V GEMM: grid (128, 24) = 3072 blocks. Per XCD: seg-major order.
// seg 0 -> Q (bf16 + norms), seg 1 -> K (hi/lo + norms), seg 2 -> V^T bf16.
// ---------------------------------------------------------------------------
__global__ __launch_bounds__(256) void gemm_qkv(
    const unsigned short* __restrict__ xbf,
    const unsigned short* __restrict__ wq, const unsigned short* __restrict__ wk,
    const unsigned short* __restrict__ wv,
    const float* __restrict__ bq, const float* __restrict__ bk,
    const float* __restrict__ bv,
    unsigned short* __restrict__ qbf, float* __restrict__ qnorms,
    unsigned short* __restrict__ khi, unsigned short* __restrict__ klo,
    float* __restrict__ knorms,
    unsigned short* __restrict__ vt) {
  __shared__ __align__(16) char smem[65536];
  unsigned short* S = (unsigned short*)smem;
  const int tid = threadIdx.x, lane = tid & 63;
  const int w = tid >> 6, wr = w >> 1, wc = w & 1;
  const int g = lane >> 4, li = lane & 15;
  const int flat = blockIdx.y * gridDim.x + blockIdx.x;   // 0..3071
  const int xcd = flat & 7, loc = flat >> 3;              // 0..383
  const int seg = loc >> 7;                               // 0..2
  const int idx = loc & 127;                              // 16 m x 8 n
  const int m0 = (xcd * 16 + (idx >> 3)) * 128;
  const int n0 = (idx & 7) * 128;                         // within seg
  const unsigned short* W = seg == 0 ? wq : seg == 1 ? wk : wv;
  const float* bias = seg == 0 ? bq : seg == 1 ? bk : bv;

  GEMM_CORE(xbf, W, DD)

  float* ep = (float*)smem + w * (32 * 68);
  const int head = (n0 + wc * 64) >> 6;
  const int rbase = m0 + wr * 64;
  const int b = rbase >> 12;
  const float* biasp = bias + n0 + wc * 64;

  if (seg == 0) {
    EPI_Q(qbf, qnorms, biasp)
  } else if (seg == 1) {
    EPI_MODE2(khi, klo, knorms, biasp)
  } else {
    // MODE 1: bf16 transposed Ct[(b*16+head)*64 + d][4096]
#pragma unroll
    for (int jh = 0; jh < 2; ++jh) {
#pragma unroll
      for (int i = 0; i < 4; ++i)
#pragma unroll
        for (int j2 = 0; j2 < 2; ++j2) {
          const int j = jh * 2 + j2;
          const float bz = biasp[j * 16 + li];
          f32x4 t;
          t[0] = acc[i][j][0] + bz; t[1] = acc[i][j][1] + bz;
          t[2] = acc[i][j][2] + bz; t[3] = acc[i][j][3] + bz;
          *(f32x4*)&ep[(j2 * 16 + li) * 68 + i * 16 + 4 * g] = t;
        }
      const int rd = lane >> 3, cc = lane & 7;
#pragma unroll
      for (int p = 0; p < 4; ++p) {
        const int dl = p * 8 + rd;
        float v[8];
        *(f32x4*)&v[0] = *(const f32x4*)&ep[dl * 68 + cc * 8];
        *(f32x4*)&v[4] = *(const f32x4*)&ep[dl * 68 + cc * 8 + 4];
        u16x8 hv;
#pragma unroll
        for (int e = 0; e < 8; ++e) hv[e] = f2bf(v[e]);
        const int dh = jh * 32 + dl;
        const int lg = rbase & 4095;
        *(u16x8*)&vt[((size_t)(b * 16 + head) * 64 + dh) * 4096 + lg + cc * 8] = hv;
      }
    }
  }
}

// ---------------------------------------------------------------------------
// Output GEMM (fp32 row-major): C = attn @ Wo^T + bo. grid (128, 8).
// ---------------------------------------------------------------------------
__global__ __launch_bounds__(256) void gemm_out(
    const unsigned short* __restrict__ A, const unsigned short* __restrict__ Wo,
    const float* __restrict__ bias, float* __restrict__ Cf) {
  __shared__ __align__(16) char smem[65536];
  unsigned short* S = (unsigned short*)smem;
  const int tid = threadIdx.x, lane = tid & 63;
  const int w = tid >> 6, wr = w >> 1, wc = w & 1;
  const int g = lane >> 4, li = lane & 15;
  const int flat = blockIdx.y * gridDim.x + blockIdx.x;   // 0..1023
  const int xcd = flat & 7, loc = flat >> 3;
  const int m0 = ((xcd << 4) + (loc & 15)) * 128;
  const int n0 = (loc >> 4) * 128;

  GEMM_CORE(A, Wo, DD)

  float* ep = (float*)smem + w * (32 * 68);
  const int rbase = m0 + wr * 64;
#pragma unroll
  for (int jh = 0; jh < 2; ++jh) {
#pragma unroll
    for (int i2 = 0; i2 < 2; ++i2) {
      const int i = jh * 2 + i2;
#pragma unroll
      for (int j = 0; j < 4; ++j) {
        const float bz = bias[n0 + wc * 64 + j * 16 + li];
#pragma unroll
        for (int r = 0; r < 4; ++r)
          ep[(i2 * 16 + 4 * g + r) * 68 + j * 16 + li] = acc[i][j][r] + bz;
      }
    }
    const int rrow = lane >> 4, cc = lane & 15;
#pragma unroll
    for (int p = 0; p < 8; ++p) {
      const int row = p * 4 + rrow;
      f32x4 v = *(const f32x4*)&ep[row * 68 + cc * 4];
      *(f32x4*)&Cf[(size_t)(rbase + jh * 32 + row) * 1024 + n0 + wc * 64 + cc * 4] = v;
    }
  }
}

// ---------------------------------------------------------------------------
// kv + ksum. grid (64 bh, NSPLIT), 256 thr / 4 waves. 2-TERM proj split:
// oh*(khi + klo). phi via single v_exp_f32. (r11 structure, unchanged)
// ---------------------------------------------------------------------------
__global__ __launch_bounds__(256, 2) void kv_mfma(
    const unsigned short* __restrict__ khi, const unsigned short* __restrict__ klo,
    const float* __restrict__ knorms, const unsigned short* __restrict__ vt,
    const unsigned short* __restrict__ orfhi,
    float* __restrict__ pkv, float* __restrict__ pksum) {
  __shared__ __align__(16) unsigned short KsHi[64 * 64], KsLo[64 * 64];
  __shared__ __align__(16) unsigned short VT[64 * 64], KphiT[64 * 64];
  __shared__ float ns[64];
  const int tid = threadIdx.x, lane = tid & 63, w = tid >> 6;
  const int g = lane >> 4, li = lane & 15;
  const int bh = blockIdx.x, sp = blockIdx.y;
  const int srow8 = lane >> 3;
  const int scol  = ((lane & 7) ^ srow8) << 3;
  const int sx = (li & 7) << 3;

  bf16x8 oh[4][2];
#pragma unroll
  for (int p = 0; p < 4; ++p)
#pragma unroll
    for (int kk = 0; kk < 2; ++kk)
      oh[p][kk] = *(const bf16x8*)
          &orfhi[(size_t)(p * 64 + w * 16 + li) * 64 + kk * 32 + g * 8];

  f32x4 kvacc[4][4] = {};
  float ksacc[4][4] = {};

  for (int c = 0; c < LCH / 64; ++c) {
    const int l0 = sp * LCH + c * 64;
    __syncthreads();
    {
      const size_t kb = ((size_t)bh * 4096 + l0 + w * 16 + srow8) * 64 + scol;
      gload16(khi + kb, &KsHi[(w * 16) * 64]);
      gload16(khi + kb + 8 * 64, &KsHi[(w * 16 + 8) * 64]);
      gload16(klo + kb, &KsLo[(w * 16) * 64]);
      gload16(klo + kb + 8 * 64, &KsLo[(w * 16 + 8) * 64]);
      const size_t vb = ((size_t)bh * 64 + w * 16 + srow8) * 4096 + l0 + scol;
      gload16(vt + vb, &VT[(w * 16) * 64]);
      gload16(vt + vb + (size_t)8 * 4096, &VT[(w * 16 + 8) * 64]);
      if (tid < 64) ns[tid] = knorms[(size_t)bh * 4096 + l0 + tid];
    }
    __syncthreads();

#pragma unroll
    for (int p = 0; p < 4; ++p) {
      f32x4 pr[4] = {};
      __builtin_amdgcn_s_setprio(1);
#pragma unroll
      for (int kk = 0; kk < 2; ++kk) {
        const int cx = (kk * 32 + g * 8) ^ sx;
#pragma unroll
        for (int lf = 0; lf < 4; ++lf) {
          const bf16x8 bh2 = *(const bf16x8*)&KsHi[(lf * 16 + li) * 64 + cx];
          const bf16x8 bl2 = *(const bf16x8*)&KsLo[(lf * 16 + li) * 64 + cx];
          pr[lf] = mfma16(oh[p][kk], bh2, pr[lf]);
          pr[lf] = mfma16(oh[p][kk], bl2, pr[lf]);
        }
      }
      __builtin_amdgcn_s_setprio(0);
#pragma unroll
      for (int lf = 0; lf < 4; ++lf) {
        const float nrm = ns[lf * 16 + li];
#pragma unroll
        for (int r = 0; r < 4; ++r) {
          float phi = fexp2(pr[lf][r] - nrm) + EPSF;
          ksacc[p][r] += phi;
          const int row = w * 16 + 4 * g + r;
          KphiT[row * 64 + SWZ(row, lf * 16 + li)] = f2bf(phi);
        }
      }
      __builtin_amdgcn_s_setprio(1);
#pragma unroll
      for (int kk = 0; kk < 2; ++kk) {
        const int cx = (kk * 32 + g * 8) ^ sx;
        const bf16x8 a = *(const bf16x8*)&KphiT[(w * 16 + li) * 64 + cx];
#pragma unroll
        for (int df = 0; df < 4; ++df) {
          const bf16x8 bv = *(const bf16x8*)&VT[(df * 16 + li) * 64 + cx];
          kvacc[p][df] = mfma16(a, bv, kvacc[p][df]);
        }
      }
      __builtin_amdgcn_s_setprio(0);
    }
  }
  float* kvo = pkv + ((size_t)sp * 64 + bh) * (MMF * DK);
#pragma unroll
  for (int p = 0; p < 4; ++p)
#pragma unroll
    for (int df = 0; df < 4; ++df)
#pragma unroll
      for (int r = 0; r < 4; ++r)
        kvo[(p * 64 + w * 16 + 4 * g + r) * DK + df * 16 + li] = kvacc[p][df][r];

  float* kso = pksum + ((size_t)sp * 64 + bh) * MMF;
#pragma unroll
  for (int p = 0; p < 4; ++p)
#pragma unroll
    for (int r = 0; r < 4; ++r) {
      float s = ksacc[p][r];
      s += __shfl_xor(s, 1); s += __shfl_xor(s, 2);
      s += __shfl_xor(s, 4); s += __shfl_xor(s, 8);
      if (li == 0) kso[p * 64 + w * 16 + 4 * g + r] = s;
    }
}

// ---------------------------------------------------------------------------
// reduce partials; emit kv TRANSPOSED bf16 kvT[bh][d][m] + ksum fp32
// ---------------------------------------------------------------------------
__global__ __launch_bounds__(256) void reduce_parts(
    const float* __restrict__ pkv, unsigned short* __restrict__ kvT,
    const float* __restrict__ pks, float* __restrict__ ksg) {
  const int id = blockIdx.x * 256 + threadIdx.x;   // grid 1024 -> 262144
  {
    const int bh = id >> 12, rest = id & 4095;
    const int m0 = (rest >> 6) << 2, d = rest & 63;
    float s0 = 0.f, s1 = 0.f, s2 = 0.f, s3 = 0.f;
#pragma unroll
    for (int sp = 0; sp < NSPLIT; ++sp) {
      const float* p = pkv + (size_t)(sp * 64 + bh) * (MMF * DK) + d;
      s0 += p[(m0 + 0) * DK]; s1 += p[(m0 + 1) * DK];
      s2 += p[(m0 + 2) * DK]; s3 += p[(m0 + 3) * DK];
    }
    ushort4 o;
    o.x = f2bf(s0); o.y = f2bf(s1); o.z = f2bf(s2); o.w = f2bf(s3);
    *(ushort4*)&kvT[((size_t)bh * DK + d) * MMF + m0] = o;
  }
  if (id < 4096) {
    float4 s = {0.f, 0.f, 0.f, 0.f};
#pragma unroll
    for (int sp = 0; sp < NSPLIT; ++sp) {
      float4 v = *(const float4*)&pks[(size_t)sp * 64 * MMF + id * 4];
      s.x += v.x; s.y += v.y; s.z += v.z; s.w += v.w;
    }
    *(float4*)&ksg[id * 4] = s;
  }
}

// ---------------------------------------------------------------------------
// q_phi + num/den -> attn (bf16). grid (64 bh, 32 l-blocks), 512 threads.
// Q single-bf16 -> 1-term proj (8 MFMA per pass instead of 16).
// ---------------------------------------------------------------------------
__global__ __launch_bounds__(512, 4) void qattn_mfma(
    const unsigned short* __restrict__ qbf,
    const float* __restrict__ qnorms,
    const unsigned short* __restrict__ orfhi,
    const unsigned short* __restrict__ kvT, const float* __restrict__ ksg,
    unsigned short* __restrict__ attn) {
  __shared__ __align__(16) unsigned short OHi[256 * 64];    // 32 KB
  __shared__ __align__(16) unsigned short KvTs[64 * 256];   // 32 KB
  __shared__ __align__(16) unsigned short Qphi[8][16 * 64]; // 16 KB
  const int tid = threadIdx.x, lane = tid & 63, w = tid >> 6;
  const int g = lane >> 4, li = lane & 15;
  const int bh = blockIdx.x, lb = blockIdx.y;
  const int b = bh >> 4, h = bh & 15;
  const int srow8 = lane >> 3;
  const int scol  = ((lane & 7) ^ srow8) << 3;
  const int sx = (li & 7) << 3;

#pragma unroll
  for (int q = 0; q < 4; ++q) {
    const size_t o = (size_t)(w * 32 + q * 8 + srow8) * 64 + scol;
    gload16(orfhi + o, &OHi[(w * 32 + q * 8) * 64]);
  }
  {
    const int srow2 = lane >> 5;
#pragma unroll
    for (int q = 0; q < 4; ++q) {
      const int d0 = w * 8 + q * 2, dr = d0 + srow2;
      gload16(kvT + ((size_t)bh * DK + dr) * MMF + (((lane & 31) ^ (dr & 7)) << 3),
              &KvTs[d0 * 256]);
    }
  }

  float ksr[4][4];
#pragma unroll
  for (int p = 0; p < 4; ++p)
#pragma unroll
    for (int mf = 0; mf < 4; ++mf)
      ksr[p][mf] = ksg[(size_t)bh * MMF + p * 64 + mf * 16 + li];
  const float4 nr =
      *(const float4*)&qnorms[(size_t)bh * 4096 + lb * 128 + w * 16 + 4 * g];
  bf16x8 qh[2];
  {
    const size_t qr = ((size_t)bh * 4096 + lb * 128 + w * 16 + li) * 64 + g * 8;
    qh[0] = *(const bf16x8*)&qbf[qr];
    qh[1] = *(const bf16x8*)&qbf[qr + 32];
  }
  __syncthreads();

  f32x4 numacc[4] = {};
  float denacc[4] = {};

#pragma unroll
  for (int p = 0; p < 4; ++p) {
    f32x4 pr[4] = {};
    __builtin_amdgcn_s_setprio(1);
#pragma unroll
    for (int kk = 0; kk < 2; ++kk) {
      const int cx = (kk * 32 + g * 8) ^ sx;
#pragma unroll
      for (int mf = 0; mf < 4; ++mf) {
        const int row = p * 64 + mf * 16 + li;
        const bf16x8 bh2 = *(const bf16x8*)&OHi[row * 64 + cx];
        pr[mf] = mfma16(qh[kk], bh2, pr[mf]);
      }
    }
    __builtin_amdgcn_s_setprio(0);
#pragma unroll
    for (int mf = 0; mf < 4; ++mf) {
      const float ks = ksr[p][mf];
#pragma unroll
      for (int r = 0; r < 4; ++r) {
        float phi = fexp2(pr[mf][r] - nr[r]) + EPSF;
        denacc[r] += phi * ks;
        const int row = 4 * g + r;
        Qphi[w][row * 64 + SWZ(row, mf * 16 + li)] = f2bf(phi);
      }
    }
    __builtin_amdgcn_s_setprio(1);
#pragma unroll
    for (int kk = 0; kk < 2; ++kk) {
      const int cx = (kk * 32 + g * 8) ^ sx;
      const bf16x8 a = *(const bf16x8*)&Qphi[w][li * 64 + cx];
#pragma unroll
      for (int df = 0; df < 4; ++df) {
        const bf16x8 bv = *(const bf16x8*)
            &KvTs[(df * 16 + li) * 256 + (((p * 8 + kk * 4 + g) ^ (li & 7)) << 3)];
        numacc[df] = mfma16(a, bv, numacc[df]);
      }
    }
    __builtin_amdgcn_s_setprio(0);
  }
  float den[4];
#pragma unroll
  for (int r = 0; r < 4; ++r) {
    float s = denacc[r];
    s += __shfl_xor(s, 1); s += __shfl_xor(s, 2);
    s += __shfl_xor(s, 4); s += __shfl_xor(s, 8);
    den[r] = s;
  }
  unsigned short* ab =
      attn + ((size_t)b * 4096 + lb * 128) * 1024 + h * 64;
#pragma unroll
  for (int df = 0; df < 4; ++df)
#pragma unroll
    for (int r = 0; r < 4; ++r)
      ab[(size_t)(w * 16 + 4 * g + r) * 1024 + df * 16 + li] =
          f2bf(numacc[df][r] / den[r]);
}

// ---------------------------------------------------------------------------
extern "C" void kernel_launch(void* const* d_in, const int* in_sizes, int n_in,
                              void* d_out, int out_size, void* d_ws, size_t ws_size,
                              hipStream_t stream) {
  (void)in_sizes; (void)n_in; (void)out_size; (void)ws_size;
  const float* x   = (const float*)d_in[0];
  const float* Wq  = (const float*)d_in[1];
  const float* bq  = (const float*)d_in[2];
  const float* Wk  = (const float*)d_in[3];
  const float* bk  = (const float*)d_in[4];
  const float* Wv  = (const float*)d_in[5];
  const float* bv  = (const float*)d_in[6];
  const float* Wo  = (const float*)d_in[7];
  const float* bo  = (const float*)d_in[8];
  const float* orf = (const float*)d_in[9];
  float* out = (float*)d_out;

  const size_t ND = (size_t)BB * LL * DD;   // 16,777,216
  char* base = (char*)d_ws;
  size_t off = 0;
  auto alloc = [&](size_t bytes) -> char* {
    char* p = base + off;
    off += (bytes + 255) & ~(size_t)255;
    return p;
  };
  unsigned short* wqbf   = (unsigned short*)alloc((size_t)DD * DD * 2);
  unsigned short* wkbf   = (unsigned short*)alloc((size_t)DD * DD * 2);
  unsigned short* wvbf   = (unsigned short*)alloc((size_t)DD * DD * 2);
  unsigned short* wobf   = (unsigned short*)alloc((size_t)DD * DD * 2);
  unsigned short* orfhi  = (unsigned short*)alloc((size_t)MMF * DK * 2);
  unsigned short* xbf    = (unsigned short*)alloc(ND * 2);   // aliased by pkv
  unsigned short* qbf    = (unsigned short*)alloc(ND * 2);
  unsigned short* khi    = (unsigned short*)alloc(ND * 2);   // aliased by attnbf
  unsigned short* klo    = (unsigned short*)alloc(ND * 2);
  unsigned short* vtbuf  = (unsigned short*)alloc(ND * 2);
  float*          qnorms = (float*)alloc((size_t)64 * LL * 4);
  float*          knorms = (float*)alloc((size_t)64 * LL * 4);
  float*          pksum  = (float*)alloc((size_t)NSPLIT * 64 * MMF * 4);
  unsigned short* kvT    = (unsigned short*)alloc((size_t)64 * DK * MMF * 2);
  float*          ksg    = (float*)alloc((size_t)64 * MMF * 4);
  float*          pkv    = (float*)xbf;            // 33.5 MB, exact alias
  unsigned short* attnbf = khi;                    // khi dead after kv_mfma

  cvt_all<<<20496, 256, 0, stream>>>(x, Wq, Wk, Wv, Wo, orf,
                                     xbf, wqbf, wkbf, wvbf, wobf, orfhi);

  gemm_qkv<<<dim3(128, 24), 256, 0, stream>>>(
      xbf, wqbf, wkbf, wvbf, bq, bk, bv,
      qbf, qnorms, khi, klo, knorms, vtbuf);

  kv_mfma<<<dim3(64, NSPLIT), 256, 0, stream>>>(khi, klo, knorms, vtbuf,
                                                orfhi, pkv, pksum);
  reduce_parts<<<1024, 256, 0, stream>>>(pkv, kvT, pksum, ksg);
  qattn_mfma<<<dim3(64, 32), 512, 0, stream>>>(qbf, qnorms, orfhi,
                                               kvT, ksg, attnbf);

  gemm_out<<<dim3(128, 8), 256, 0, stream>>>(attnbf, wobf, bo, out);
}

// Round 17
// 280.609 us; speedup vs baseline: 1.0829x; 1.0172x over previous
//
#include <hip/hip_runtime.h>
#include <hip/hip_bf16.h>
#include <math.h>

// Problem constants
#define HH 16
#define BB 4
#define LL 4096
#define DD 1024
#define DK 64
#define MMF 256
#define EPSF 1e-6f
// orf scale: 64^-0.25 * log2(e)  (phi computed as exp2)
#define KSCALE (0.35355339059327373f * 1.4426950408889634f)
// norm scale: 1/(2*sqrt(64)) * log2(e)
#define NORMSCALE (0.0625f * 1.4426950408889634f)
#define NSPLIT 8
#define LCH (LL / NSPLIT)             // 512 rows of L per kv block

typedef __attribute__((ext_vector_type(8))) short bf16x8;
typedef __attribute__((ext_vector_type(4))) float f32x4;
typedef __attribute__((ext_vector_type(8))) unsigned short u16x8;

// native RNE cast -> compiler can pair into v_cvt_pk_bf16_f32 (m240)
__device__ __forceinline__ unsigned short f2bf(float f) {
  __hip_bfloat16 h = __float2bfloat16(f);
  unsigned short u;
  __builtin_memcpy(&u, &h, 2);
  return u;
}
__device__ __forceinline__ float bf2f(unsigned short h) {
  union { unsigned u; float f; } v; v.u = ((unsigned)h) << 16;
  return v.f;
}
__device__ __forceinline__ f32x4 mfma16(bf16x8 a, bf16x8 b, f32x4 c) {
  return __builtin_amdgcn_mfma_f32_16x16x32_bf16(a, b, c, 0, 0, 0);
}
// single v_exp_f32 (exp2f routes through OCML's precise multi-inst path)
__device__ __forceinline__ float fexp2(float x) {
  return __builtin_amdgcn_exp2f(x);
}
// async global->LDS, 16B per lane; dst is wave-uniform base (lane x16 implicit)
__device__ __forceinline__ void gload16(const unsigned short* g, unsigned short* l) {
  __builtin_amdgcn_global_load_lds(
      (const __attribute__((address_space(1))) void*)g,
      (__attribute__((address_space(3))) void*)l, 16, 0, 0);
}
// T2 swizzle for 64-element bf16 rows (element-index xor)
#define SWZ(row, col) ((col) ^ (((row) & 7) << 3))

// ---------------------------------------------------------------------------
// merged fp32->bf16 conversion, 8 elems/thread: x (8192 blks) + 4 weights
// (512 each) + orf (8, scaled). One dispatch, 10248 blocks.
// ---------------------------------------------------------------------------
__global__ __launch_bounds__(256) void cvt_all(
    const float* __restrict__ x,
    const float* __restrict__ Wq, const float* __restrict__ Wk,
    const float* __restrict__ Wv, const float* __restrict__ Wo,
    const float* __restrict__ orf,
    unsigned short* __restrict__ xbf,
    unsigned short* __restrict__ wqbf, unsigned short* __restrict__ wkbf,
    unsigned short* __restrict__ wvbf, unsigned short* __restrict__ wobf,
    unsigned short* __restrict__ orfhi) {
  const int bid = blockIdx.x;
  const float* s;
  unsigned short* d;
  int base;
  float scale = 1.0f;
  if (bid < 8192)       { s = x;   d = xbf;   base = bid; }
  else if (bid < 8704)  { s = Wq;  d = wqbf;  base = bid - 8192; }
  else if (bid < 9216)  { s = Wk;  d = wkbf;  base = bid - 8704; }
  else if (bid < 9728)  { s = Wv;  d = wvbf;  base = bid - 9216; }
  else if (bid < 10240) { s = Wo;  d = wobf;  base = bid - 9728; }
  else                  { s = orf; d = orfhi; base = bid - 10240; scale = KSCALE; }
  const int i = (base * 256 + threadIdx.x) * 8;
  float4 v0 = *(const float4*)&s[i];
  float4 v1 = *(const float4*)&s[i + 4];
  u16x8 o;
  o[0] = f2bf(v0.x * scale); o[1] = f2bf(v0.y * scale);
  o[2] = f2bf(v0.z * scale); o[3] = f2bf(v0.w * scale);
  o[4] = f2bf(v1.x * scale); o[5] = f2bf(v1.y * scale);
  o[6] = f2bf(v1.z * scale); o[7] = f2bf(v1.w * scale);
  *(u16x8*)&d[i] = o;
}

// ---------------------------------------------------------------------------
// Shared GEMM core (r11-proven): 128x128 tile, BK=64, 4 waves (2x2), dbuf
// 64KB LDS, stage-next-first + counted vmcnt(8), 2 barriers/K-tile.
// ---------------------------------------------------------------------------
#define GEMM_CORE(A_, W_, K_)                                                  \
  f32x4 acc[4][4] = {};                                                        \
  const int srow8 = lane >> 3;                                                 \
  const int scol  = ((lane & 7) ^ srow8) << 3;                                 \
  const unsigned short* Ag = (A_) + (size_t)(m0 + w * 32 + srow8) * (K_) + scol;\
  const unsigned short* Wg = (W_) + (size_t)(n0 + w * 32 + srow8) * (K_) + scol;\
  const int nt = (K_) >> 6;                                                    \
  _Pragma("unroll")                                                            \
  for (int j = 0; j < 4; ++j) {                                                \
    gload16(Ag + (size_t)j * 8 * (K_), S + (w * 32 + j * 8) * 64);             \
    gload16(Wg + (size_t)j * 8 * (K_), S + 8192 + (w * 32 + j * 8) * 64);      \
  }                                                                            \
  for (int t = 0; t < nt; ++t) {                                               \
    const int co = (t & 1) << 14;                                              \
    const int no = co ^ 16384;                                                 \
    if (t + 1 < nt) {                                                          \
      const int k1 = (t + 1) << 6;                                             \
      _Pragma("unroll")                                                        \
      for (int j = 0; j < 4; ++j) {                                            \
        gload16(Ag + (size_t)j * 8 * (K_) + k1, S + no + (w * 32 + j * 8) * 64);\
        gload16(Wg + (size_t)j * 8 * (K_) + k1,                                \
                S + no + 8192 + (w * 32 + j * 8) * 64);                        \
      }                                                                        \
      asm volatile("s_waitcnt vmcnt(8)" ::: "memory");                         \
    } else {                                                                   \
      asm volatile("s_waitcnt vmcnt(0)" ::: "memory");                         \
    }                                                                          \
    __builtin_amdgcn_s_barrier();                                              \
    const int sx = (li & 7) << 3;                                              \
    _Pragma("unroll")                                                          \
    for (int kk = 0; kk < 2; ++kk) {                                           \
      const int c = (kk * 32 + g * 8) ^ sx;                                    \
      bf16x8 af[4], bfr[4];                                                    \
      _Pragma("unroll")                                                        \
      for (int i = 0; i < 4; ++i)                                              \
        af[i] = *(const bf16x8*)&S[co + (wr * 64 + i * 16 + li) * 64 + c];     \
      _Pragma("unroll")                                                        \
      for (int j = 0; j < 4; ++j)                                              \
        bfr[j] = *(const bf16x8*)&S[co + 8192 + (wc * 64 + j * 16 + li) * 64 + c];\
      _Pragma("unroll")                                                        \
      for (int i = 0; i < 4; ++i)                                              \
        _Pragma("unroll")                                                      \
        for (int j = 0; j < 4; ++j)                                            \
          acc[i][j] = mfma16(af[i], bfr[j], acc[i][j]);                        \
    }                                                                          \
    asm volatile("s_waitcnt lgkmcnt(0)" ::: "memory");                         \
    __builtin_amdgcn_s_barrier();                                              \
  }

// K-path epilogue: hi/lo bf16 + norms
#define EPI_MODE2(C1_, C2_, Cn_, biasp_)                                       \
  _Pragma("unroll")                                                            \
  for (int jh = 0; jh < 2; ++jh) {                                             \
    _Pragma("unroll")                                                          \
    for (int i2 = 0; i2 < 2; ++i2) {                                           \
      const int i = jh * 2 + i2;                                               \
      _Pragma("unroll")                                                        \
      for (int j = 0; j < 4; ++j) {                                            \
        const float bz = (biasp_)[j * 16 + li];                                \
        _Pragma("unroll")                                                      \
        for (int r = 0; r < 4; ++r)                                            \
          ep[(i2 * 16 + 4 * g + r) * 68 + j * 16 + li] = acc[i][j][r] + bz;    \
      }                                                                        \
    }                                                                          \
    const int rrow = lane >> 3, cc = lane & 7;                                 \
    _Pragma("unroll")                                                          \
    for (int p = 0; p < 4; ++p) {                                              \
      const int row = p * 8 + rrow;                                            \
      float v[8];                                                              \
      *(f32x4*)&v[0] = *(const f32x4*)&ep[row * 68 + cc * 8];                  \
      *(f32x4*)&v[4] = *(const f32x4*)&ep[row * 68 + cc * 8 + 4];              \
      float np = 0.f;                                                          \
      u16x8 hv, lv;                                                            \
      _Pragma("unroll")                                                        \
      for (int e = 0; e < 8; ++e) {                                            \
        float vv = v[e];                                                       \
        np += vv * vv;                                                         \
        unsigned short h2 = f2bf(vv);                                          \
        hv[e] = h2;                                                            \
        lv[e] = f2bf(vv - bf2f(h2));                                           \
      }                                                                        \
      const int lg = (rbase + jh * 32 + row) & 4095;                           \
      const size_t rowb = (size_t)(b * 16 + head) * 4096 + lg;                 \
      *(u16x8*)&(C1_)[rowb * 64 + cc * 8] = hv;                                \
      *(u16x8*)&(C2_)[rowb * 64 + cc * 8] = lv;                                \
      np += __shfl_xor(np, 1);                                                 \
      np += __shfl_xor(np, 2);                                                 \
      np += __shfl_xor(np, 4);                                                 \
      if (cc == 0) (Cn_)[rowb] = np * NORMSCALE;                               \
    }                                                                          \
  }

// Q-path epilogue: single bf16 + norms (lo dropped — q-side phi error
// ratio-cancels in num/den; r5/r16 evidence)
#define EPI_Q(C1_, Cn_, biasp_)                                                \
  _Pragma("unroll")                                                            \
  for (int jh = 0; jh < 2; ++jh) {                                             \
    _Pragma("unroll")                                                          \
    for (int i2 = 0; i2 < 2; ++i2) {                                           \
      const int i = jh * 2 + i2;                                               \
      _Pragma("unroll")                                                        \
      for (int j = 0; j < 4; ++j) {                                            \
        const float bz = (biasp_)[j * 16 + li];                                \
        _Pragma("unroll")                                                      \
        for (int r = 0; r < 4; ++r)                                            \
          ep[(i2 * 16 + 4 * g + r) * 68 + j * 16 + li] = acc[i][j][r] + bz;    \
      }                                                                        \
    }                                                                          \
    const int rrow = lane >> 3, cc = lane & 7;                                 \
    _Pragma("unroll")                                                          \
    for (int p = 0; p < 4; ++p) {                                              \
      const int row = p * 8 + rrow;                                            \
      float v[8];                                                              \
      *(f32x4*)&v[0] = *(const f32x4*)&ep[row * 68 + cc * 8];                  \
      *(f32x4*)&v[4] = *(const f32x4*)&ep[row * 68 + cc * 8 + 4];              \
      float np = 0.f;                                                          \
      u16x8 hv;                                                                \
      _Pragma("unroll")                                                        \
      for (int e = 0; e < 8; ++e) {                                            \
        float vv = v[e];                                                       \
        np += vv * vv;                                                         \
        hv[e] = f2bf(vv);                                                      \
      }                                                                        \
      const int lg = (rbase + jh * 32 + row) & 4095;                           \
      const size_t rowb = (size_t)(b * 16 + head) * 4096 + lg;                 \
      *(u16x8*)&(C1_)[rowb * 64 + cc * 8] = hv;                                \
      np += __shfl_xor(np, 1);                                                 \
      np += __shfl_xor(np, 2);                                                 \
      np += __shfl_xor(np, 4);                                                 \
      if (cc == 0) (Cn_)[rowb] = np * NORMSCALE;                               \
    }                                                                          \
  }

// ---------------------------------------------------------------------------
// Merged Q/K/V GEMM: grid (128, 24) = 3072 blocks. Per XCD: seg-major order.
// seg 0 -> Q (bf16 + norms), seg 1 -> K (hi/lo + norms), seg 2 -> V^T bf16.
// ---------------------------------------------------------------------------
__global__ __launch_bounds__(256) void gemm_qkv(
    const unsigned short* __restrict__ xbf,
    const unsigned short* __restrict__ wq, const unsigned short* __restrict__ wk,
    const unsigned short* __restrict__ wv,
    const float* __restrict__ bq, const float* __restrict__ bk,
    const float* __restrict__ bv,
    unsigned short* __restrict__ qbf, float* __restrict__ qnorms,
    unsigned short* __restrict__ khi, unsigned short* __restrict__ klo,
    float* __restrict__ knorms,
    unsigned short* __restrict__ vt) {
  __shared__ __align__(16) char smem[65536];
  unsigned short* S = (unsigned short*)smem;
  const int tid = threadIdx.x, lane = tid & 63;
  const int w = tid >> 6, wr = w >> 1, wc = w & 1;
  const int g = lane >> 4, li = lane & 15;
  const int flat = blockIdx.y * gridDim.x + blockIdx.x;   // 0..3071
  const int xcd = flat & 7, loc = flat >> 3;              // 0..383
  const int seg = loc >> 7;                               // 0..2
  const int idx = loc & 127;                              // 16 m x 8 n
  const int m0 = (xcd * 16 + (idx >> 3)) * 128;
  const int n0 = (idx & 7) * 128;                         // within seg
  const unsigned short* W = seg == 0 ? wq : seg == 1 ? wk : wv;
  const float* bias = seg == 0 ? bq : seg == 1 ? bk : bv;

  GEMM_CORE(xbf, W, DD)

  float* ep = (float*)smem + w * (32 * 68);
  const int head = (n0 + wc * 64) >> 6;
  const int rbase = m0 + wr * 64;
  const int b = rbase >> 12;
  const float* biasp = bias + n0 + wc * 64;

  if (seg == 0) {
    EPI_Q(qbf, qnorms, biasp)
  } else if (seg == 1) {
    EPI_MODE2(khi, klo, knorms, biasp)
  } else {
    // MODE 1: bf16 transposed Ct[(b*16+head)*64 + d][4096]
#pragma unroll
    for (int jh = 0; jh < 2; ++jh) {
#pragma unroll
      for (int i = 0; i < 4; ++i)
#pragma unroll
        for (int j2 = 0; j2 < 2; ++j2) {
          const int j = jh * 2 + j2;
          const float bz = biasp[j * 16 + li];
          f32x4 t;
          t[0] = acc[i][j][0] + bz; t[1] = acc[i][j][1] + bz;
          t[2] = acc[i][j][2] + bz; t[3] = acc[i][j][3] + bz;
          *(f32x4*)&ep[(j2 * 16 + li) * 68 + i * 16 + 4 * g] = t;
        }
      const int rd = lane >> 3, cc = lane & 7;
#pragma unroll
      for (int p = 0; p < 4; ++p) {
        const int dl = p * 8 + rd;
        float v[8];
        *(f32x4*)&v[0] = *(const f32x4*)&ep[dl * 68 + cc * 8];
        *(f32x4*)&v[4] = *(const f32x4*)&ep[dl * 68 + cc * 8 + 4];
        u16x8 hv;
#pragma unroll
        for (int e = 0; e < 8; ++e) hv[e] = f2bf(v[e]);
        const int dh = jh * 32 + dl;
        const int lg = rbase & 4095;
        *(u16x8*)&vt[((size_t)(b * 16 + head) * 64 + dh) * 4096 + lg + cc * 8] = hv;
      }
    }
  }
}

// ---------------------------------------------------------------------------
// Output GEMM (fp32 row-major): C = attn @ Wo^T + bo. grid (128, 8).
// ---------------------------------------------------------------------------
__global__ __launch_bounds__(256) void gemm_out(
    const unsigned short* __restrict__ A, const unsigned short* __restrict__ Wo,
    const float* __restrict__ bias, float* __restrict__ Cf) {
  __shared__ __align__(16) char smem[65536];
  unsigned short* S = (unsigned short*)smem;
  const int tid = threadIdx.x, lane = tid & 63;
  const int w = tid >> 6, wr = w >> 1, wc = w & 1;
  const int g = lane >> 4, li = lane & 15;
  const int flat = blockIdx.y * gridDim.x + blockIdx.x;   // 0..1023
  const int xcd = flat & 7, loc = flat >> 3;
  const int m0 = ((xcd << 4) + (loc & 15)) * 128;
  const int n0 = (loc >> 4) * 128;

  GEMM_CORE(A, Wo, DD)

  float* ep = (float*)smem + w * (32 * 68);
  const int rbase = m0 + wr * 64;
#pragma unroll
  for (int jh = 0; jh < 2; ++jh) {
#pragma unroll
    for (int i2 = 0; i2 < 2; ++i2) {
      const int i = jh * 2 + i2;
#pragma unroll
      for (int j = 0; j < 4; ++j) {
        const float bz = bias[n0 + wc * 64 + j * 16 + li];
#pragma unroll
        for (int r = 0; r < 4; ++r)
          ep[(i2 * 16 + 4 * g + r) * 68 + j * 16 + li] = acc[i][j][r] + bz;
      }
    }
    const int rrow = lane >> 4, cc = lane & 15;
#pragma unroll
    for (int p = 0; p < 8; ++p) {
      const int row = p * 4 + rrow;
      f32x4 v = *(const f32x4*)&ep[row * 68 + cc * 4];
      *(f32x4*)&Cf[(size_t)(rbase + jh * 32 + row) * 1024 + n0 + wc * 64 + cc * 4] = v;
    }
  }
}

// ---------------------------------------------------------------------------
// kv + ksum. grid (64 bh, NSPLIT), 256 thr / 4 waves. 2-TERM proj split:
// oh*(khi + klo). phi via single v_exp_f32.
// ---------------------------------------------------------------------------
__global__ __launch_bounds__(256, 2) void kv_mfma(
    const unsigned short* __restrict__ khi, const unsigned short* __restrict__ klo,
    const float* __restrict__ knorms, const unsigned short* __restrict__ vt,
    const unsigned short* __restrict__ orfhi,
    float* __restrict__ pkv, float* __restrict__ pksum) {
  __shared__ __align__(16) unsigned short KsHi[64 * 64], KsLo[64 * 64];
  __shared__ __align__(16) unsigned short VT[64 * 64], KphiT[64 * 64];
  __shared__ float ns[64];
  const int tid = threadIdx.x, lane = tid & 63, w = tid >> 6;
  const int g = lane >> 4, li = lane & 15;
  const int bh = blockIdx.x, sp = blockIdx.y;
  const int srow8 = lane >> 3;
  const int scol  = ((lane & 7) ^ srow8) << 3;
  const int sx = (li & 7) << 3;

  bf16x8 oh[4][2];
#pragma unroll
  for (int p = 0; p < 4; ++p)
#pragma unroll
    for (int kk = 0; kk < 2; ++kk)
      oh[p][kk] = *(const bf16x8*)
          &orfhi[(size_t)(p * 64 + w * 16 + li) * 64 + kk * 32 + g * 8];

  f32x4 kvacc[4][4] = {};
  float ksacc[4][4] = {};

  for (int c = 0; c < LCH / 64; ++c) {
    const int l0 = sp * LCH + c * 64;
    __syncthreads();
    {
      const size_t kb = ((size_t)bh * 4096 + l0 + w * 16 + srow8) * 64 + scol;
      gload16(khi + kb, &KsHi[(w * 16) * 64]);
      gload16(khi + kb + 8 * 64, &KsHi[(w * 16 + 8) * 64]);
      gload16(klo + kb, &KsLo[(w * 16) * 64]);
      gload16(klo + kb + 8 * 64, &KsLo[(w * 16 + 8) * 64]);
      const size_t vb = ((size_t)bh * 64 + w * 16 + srow8) * 4096 + l0 + scol;
      gload16(vt + vb, &VT[(w * 16) * 64]);
      gload16(vt + vb + (size_t)8 * 4096, &VT[(w * 16 + 8) * 64]);
      if (tid < 64) ns[tid] = knorms[(size_t)bh * 4096 + l0 + tid];
    }
    __syncthreads();

#pragma unroll
    for (int p = 0; p < 4; ++p) {
      f32x4 pr[4] = {};
      __builtin_amdgcn_s_setprio(1);
#pragma unroll
      for (int kk = 0; kk < 2; ++kk) {
        const int cx = (kk * 32 + g * 8) ^ sx;
#pragma unroll
        for (int lf = 0; lf < 4; ++lf) {
          const bf16x8 bh2 = *(const bf16x8*)&KsHi[(lf * 16 + li) * 64 + cx];
          const bf16x8 bl2 = *(const bf16x8*)&KsLo[(lf * 16 + li) * 64 + cx];
          pr[lf] = mfma16(oh[p][kk], bh2, pr[lf]);
          pr[lf] = mfma16(oh[p][kk], bl2, pr[lf]);
        }
      }
      __builtin_amdgcn_s_setprio(0);
#pragma unroll
      for (int lf = 0; lf < 4; ++lf) {
        const float nrm = ns[lf * 16 + li];
#pragma unroll
        for (int r = 0; r < 4; ++r) {
          float phi = fexp2(pr[lf][r] - nrm) + EPSF;
          ksacc[p][r] += phi;
          const int row = w * 16 + 4 * g + r;
          KphiT[row * 64 + SWZ(row, lf * 16 + li)] = f2bf(phi);
        }
      }
      __builtin_amdgcn_s_setprio(1);
#pragma unroll
      for (int kk = 0; kk < 2; ++kk) {
        const int cx = (kk * 32 + g * 8) ^ sx;
        const bf16x8 a = *(const bf16x8*)&KphiT[(w * 16 + li) * 64 + cx];
#pragma unroll
        for (int df = 0; df < 4; ++df) {
          const bf16x8 bv = *(const bf16x8*)&VT[(df * 16 + li) * 64 + cx];
          kvacc[p][df] = mfma16(a, bv, kvacc[p][df]);
        }
      }
      __builtin_amdgcn_s_setprio(0);
    }
  }
  float* kvo = pkv + ((size_t)sp * 64 + bh) * (MMF * DK);
#pragma unroll
  for (int p = 0; p < 4; ++p)
#pragma unroll
    for (int df = 0; df < 4; ++df)
#pragma unroll
      for (int r = 0; r < 4; ++r)
        kvo[(p * 64 + w * 16 + 4 * g + r) * DK + df * 16 + li] = kvacc[p][df][r];

  float* kso = pksum + ((size_t)sp * 64 + bh) * MMF;
#pragma unroll
  for (int p = 0; p < 4; ++p)
#pragma unroll
    for (int r = 0; r < 4; ++r) {
      float s = ksacc[p][r];
      s += __shfl_xor(s, 1); s += __shfl_xor(s, 2);
      s += __shfl_xor(s, 4); s += __shfl_xor(s, 8);
      if (li == 0) kso[p * 64 + w * 16 + 4 * g + r] = s;
    }
}

// ---------------------------------------------------------------------------
// reduce partials; emit kv TRANSPOSED bf16 kvT[bh][d][m] + ksum fp32
// ---------------------------------------------------------------------------
__global__ __launch_bounds__(256) void reduce_parts(
    const float* __restrict__ pkv, unsigned short* __restrict__ kvT,
    const float* __restrict__ pks, float* __restrict__ ksg) {
  const int id = blockIdx.x * 256 + threadIdx.x;   // grid 1024 -> 262144
  {
    const int bh = id >> 12, rest = id & 4095;
    const int m0 = (rest >> 6) << 2, d = rest & 63;
    float s0 = 0.f, s1 = 0.f, s2 = 0.f, s3 = 0.f;
#pragma unroll
    for (int sp = 0; sp < NSPLIT; ++sp) {
      const float* p = pkv + (size_t)(sp * 64 + bh) * (MMF * DK) + d;
      s0 += p[(m0 + 0) * DK]; s1 += p[(m0 + 1) * DK];
      s2 += p[(m0 + 2) * DK]; s3 += p[(m0 + 3) * DK];
    }
    ushort4 o;
    o.x = f2bf(s0); o.y = f2bf(s1); o.z = f2bf(s2); o.w = f2bf(s3);
    *(ushort4*)&kvT[((size_t)bh * DK + d) * MMF + m0] = o;
  }
  if (id < 4096) {
    float4 s = {0.f, 0.f, 0.f, 0.f};
#pragma unroll
    for (int sp = 0; sp < NSPLIT; ++sp) {
      float4 v = *(const float4*)&pks[(size_t)sp * 64 * MMF + id * 4];
      s.x += v.x; s.y += v.y; s.z += v.z; s.w += v.w;
    }
    *(float4*)&ksg[id * 4] = s;
  }
}

// ---------------------------------------------------------------------------
// q_phi + num/den -> attn (bf16). grid (64 bh, 32 l-blocks), 512 threads.
// Q single-bf16 -> 1-term proj.
// ---------------------------------------------------------------------------
__global__ __launch_bounds__(512, 4) void qattn_mfma(
    const unsigned short* __restrict__ qbf,
    const float* __restrict__ qnorms,
    const unsigned short* __restrict__ orfhi,
    const unsigned short* __restrict__ kvT, const float* __restrict__ ksg,
    unsigned short* __restrict__ attn) {
  __shared__ __align__(16) unsigned short OHi[256 * 64];    // 32 KB
  __shared__ __align__(16) unsigned short KvTs[64 * 256];   // 32 KB
  __shared__ __align__(16) unsigned short Qphi[8][16 * 64]; // 16 KB
  const int tid = threadIdx.x, lane = tid & 63, w = tid >> 6;
  const int g = lane >> 4, li = lane & 15;
  const int bh = blockIdx.x, lb = blockIdx.y;
  const int b = bh >> 4, h = bh & 15;
  const int srow8 = lane >> 3;
  const int scol  = ((lane & 7) ^ srow8) << 3;
  const int sx = (li & 7) << 3;

#pragma unroll
  for (int q = 0; q < 4; ++q) {
    const size_t o = (size_t)(w * 32 + q * 8 + srow8) * 64 + scol;
    gload16(orfhi + o, &OHi[(w * 32 + q * 8) * 64]);
  }
  {
    const int srow2 = lane >> 5;
#pragma unroll
    for (int q = 0; q < 4; ++q) {
      const int d0 = w * 8 + q * 2, dr = d0 + srow2;
      gload16(kvT + ((size_t)bh * DK + dr) * MMF + (((lane & 31) ^ (dr & 7)) << 3),
              &KvTs[d0 * 256]);
    }
  }

  float ksr[4][4];
#pragma unroll
  for (int p = 0; p < 4; ++p)
#pragma unroll
    for (int mf = 0; mf < 4; ++mf)
      ksr[p][mf] = ksg[(size_t)bh * MMF + p * 64 + mf * 16 + li];
  const float4 nr =
      *(const float4*)&qnorms[(size_t)bh * 4096 + lb * 128 + w * 16 + 4 * g];
  bf16x8 qh[2];
  {
    const size_t qr = ((size_t)bh * 4096 + lb * 128 + w * 16 + li) * 64 + g * 8;
    qh[0] = *(const bf16x8*)&qbf[qr];
    qh[1] = *(const bf16x8*)&qbf[qr + 32];
  }
  __syncthreads();

  f32x4 numacc[4] = {};
  float denacc[4] = {};

#pragma unroll
  for (int p = 0; p < 4; ++p) {
    f32x4 pr[4] = {};
    __builtin_amdgcn_s_setprio(1);
#pragma unroll
    for (int kk = 0; kk < 2; ++kk) {
      const int cx = (kk * 32 + g * 8) ^ sx;
#pragma unroll
      for (int mf = 0; mf < 4; ++mf) {
        const int row = p * 64 + mf * 16 + li;
        const bf16x8 bh2 = *(const bf16x8*)&OHi[row * 64 + cx];
        pr[mf] = mfma16(qh[kk], bh2, pr[mf]);
      }
    }
    __builtin_amdgcn_s_setprio(0);
#pragma unroll
    for (int mf = 0; mf < 4; ++mf) {
      const float ks = ksr[p][mf];
#pragma unroll
      for (int r = 0; r < 4; ++r) {
        float phi = fexp2(pr[mf][r] - nr[r]) + EPSF;
        denacc[r] += phi * ks;
        const int row = 4 * g + r;
        Qphi[w][row * 64 + SWZ(row, mf * 16 + li)] = f2bf(phi);
      }
    }
    __builtin_amdgcn_s_setprio(1);
#pragma unroll
    for (int kk = 0; kk < 2; ++kk) {
      const int cx = (kk * 32 + g * 8) ^ sx;
      const bf16x8 a = *(const bf16x8*)&Qphi[w][li * 64 + cx];
#pragma unroll
      for (int df = 0; df < 4; ++df) {
        const bf16x8 bv = *(const bf16x8*)
            &KvTs[(df * 16 + li) * 256 + (((p * 8 + kk * 4 + g) ^ (li & 7)) << 3)];
        numacc[df] = mfma16(a, bv, numacc[df]);
      }
    }
    __builtin_amdgcn_s_setprio(0);
  }
  float den[4];
#pragma unroll
  for (int r = 0; r < 4; ++r) {
    float s = denacc[r];
    s += __shfl_xor(s, 1); s += __shfl_xor(s, 2);
    s += __shfl_xor(s, 4); s += __shfl_xor(s, 8);
    den[r] = s;
  }
  unsigned short* ab =
      attn + ((size_t)b * 4096 + lb * 128) * 1024 + h * 64;
#pragma unroll
  for (int df = 0; df < 4; ++df)
#pragma unroll
    for (int r = 0; r < 4; ++r)
      ab[(size_t)(w * 16 + 4 * g + r) * 1024 + df * 16 + li] =
          f2bf(numacc[df][r] / den[r]);
}

// ---------------------------------------------------------------------------
extern "C" void kernel_launch(void* const* d_in, const int* in_sizes, int n_in,
                              void* d_out, int out_size, void* d_ws, size_t ws_size,
                              hipStream_t stream) {
  (void)in_sizes; (void)n_in; (void)out_size; (void)ws_size;
  const float* x   = (const float*)d_in[0];
  const float* Wq  = (const float*)d_in[1];
  const float* bq  = (const float*)d_in[2];
  const float* Wk  = (const float*)d_in[3];
  const float* bk  = (const float*)d_in[4];
  const float* Wv  = (const float*)d_in[5];
  const float* bv  = (const float*)d_in[6];
  const float* Wo  = (const float*)d_in[7];
  const float* bo  = (const float*)d_in[8];
  const float* orf = (const float*)d_in[9];
  float* out = (float*)d_out;

  const size_t ND = (size_t)BB * LL * DD;   // 16,777,216
  char* base = (char*)d_ws;
  size_t off = 0;
  auto alloc = [&](size_t bytes) -> char* {
    char* p = base + off;
    off += (bytes + 255) & ~(size_t)255;
    return p;
  };
  unsigned short* wqbf   = (unsigned short*)alloc((size_t)DD * DD * 2);
  unsigned short* wkbf   = (unsigned short*)alloc((size_t)DD * DD * 2);
  unsigned short* wvbf   = (unsigned short*)alloc((size_t)DD * DD * 2);
  unsigned short* wobf   = (unsigned short*)alloc((size_t)DD * DD * 2);
  unsigned short* orfhi  = (unsigned short*)alloc((size_t)MMF * DK * 2);
  unsigned short* xbf    = (unsigned short*)alloc(ND * 2);   // aliased by pkv
  unsigned short* qbf    = (unsigned short*)alloc(ND * 2);
  unsigned short* khi    = (unsigned short*)alloc(ND * 2);   // aliased by attnbf
  unsigned short* klo    = (unsigned short*)alloc(ND * 2);
  unsigned short* vtbuf  = (unsigned short*)alloc(ND * 2);
  float*          qnorms = (float*)alloc((size_t)64 * LL * 4);
  float*          knorms = (float*)alloc((size_t)64 * LL * 4);
  float*          pksum  = (float*)alloc((size_t)NSPLIT * 64 * MMF * 4);
  unsigned short* kvT    = (unsigned short*)alloc((size_t)64 * DK * MMF * 2);
  float*          ksg    = (float*)alloc((size_t)64 * MMF * 4);
  float*          pkv    = (float*)xbf;            // 33.5 MB, exact alias
  unsigned short* attnbf = khi;                    // khi dead after kv_mfma

  cvt_all<<<10248, 256, 0, stream>>>(x, Wq, Wk, Wv, Wo, orf,
                                     xbf, wqbf, wkbf, wvbf, wobf, orfhi);

  gemm_qkv<<<dim3(128, 24), 256, 0, stream>>>(
      xbf, wqbf, wkbf, wvbf, bq, bk, bv,
      qbf, qnorms, khi, klo, knorms, vtbuf);

  kv_mfma<<<dim3(64, NSPLIT), 256, 0, stream>>>(khi, klo, knorms, vtbuf,
                                                orfhi, pkv, pksum);
  reduce_parts<<<1024, 256, 0, stream>>>(pkv, kvT, pksum, ksg);
  qattn_mfma<<<dim3(64, 32), 512, 0, stream>>>(qbf, qnorms, orfhi,
                                               kvT, ksg, attnbf);

  gemm_out<<<dim3(128, 8), 256, 0, stream>>>(attnbf, wobf, bo, out);
}